// Round 1
// baseline (1570.416 us; speedup 1.0000x reference)
//
#include <hip/hip_runtime.h>

// ---------------------------------------------------------------------------
// Pipeline (all intermediates bf16 stored as ushort, f32 compute):
//   x (N,C,T,V) f32 --transpose--> XTP (N,T+2,V,C) bf16 (boundary frames = 0)
//   LNXP = LN(XTP, ln1)                  [26000 rows; LN(0-row) = ln1_b]
//   QP/KP/VP = LNXP @ W{q,k,v} + b       [26000 rows  — 3x dedup vs (B,L)]
//   QA = QP @ Wqa + bqa  -> softmax over l (gathered) -> QW (B,H,L)
//   PQ[b,c] = sum_l QW * gather(QP)
//   KWL[b,h,l] = sum_c gather(KP)*PQ*Wka + bka -> softmax -> KW
//   PK[b,c] = sum_l KW * gather(KP)
//   KV  = (gather(VP) * PK_b) @ Wt + bt             [76800 rows]
//   ATT = (KV + gather(QP)) @ Wp + bp + gather(XTP) [seq residual]
//   F = LN(ATT, ffn);  G = gelu(F@W1+b1);  Y = G@W2+b2+ATT
//   TN = LN(Y, tn);    H = gelu(TN@c1_w+c1_b)
//   out[n,o,t,v] = sum_{w,i} H[(n,t,w,v),i] * c2_w[w,i,o] + c2_b[o]
// Inputs f32, output f32 (per reference dtypes).
// ---------------------------------------------------------------------------

#define DI __device__ __forceinline__

constexpr int CC   = 256;
constexpr int CL   = 75;
constexpr int CV   = 25;
constexpr int CT   = 128;
constexpr int TP   = 130;          // T+2 padded frames
constexpr int MPAD = 8 * TP * CV;  // 26000
constexpr int MBL  = 1024 * CL;    // 76800
constexpr float SM_SCALE = 0.17677669529663687f;  // 1/sqrt(32)

DI float bf2f(unsigned short u) { return __uint_as_float(((unsigned)u) << 16); }
DI float bf2f_lo(unsigned u) { return __uint_as_float(u << 16); }
DI float bf2f_hi(unsigned u) { return __uint_as_float(u & 0xffff0000u); }
DI unsigned short f2bf(float f) {
  unsigned u = __float_as_uint(f);
  u += 0x7fffu + ((u >> 16) & 1u);
  return (unsigned short)(u >> 16);
}
DI unsigned packbf(float a, float b) {
  return (unsigned)f2bf(a) | ((unsigned)f2bf(b) << 16);
}
DI float geluf(float x) { return 0.5f * x * (1.f + erff(x * 0.70710678118654752440f)); }

// (B,L) row -> padded-frame row: r=(b,l), b=n*128+t, l=w*25+v -> (n*130+t+w)*25+v
DI int arow(int r) {
  int b = r / CL;
  int l = r - b * CL;
  int w = l / CV;
  int v = l - w * CV;
  int t = b & (CT - 1);
  int n = b >> 7;
  return (n * TP + t + w) * CV + v;
}

// ---- x (N,C,T,V) f32 -> XTP (N,T+2,V,C) bf16, interior frames ----
__global__ __launch_bounds__(256) void k_transpose(const float* __restrict__ x,
                                                   unsigned short* __restrict__ xtp) {
  __shared__ float tile[32][33];
  const int n = blockIdx.z;
  const int c0 = blockIdx.x * 32;
  const int tv0 = blockIdx.y * 32;
  const int tx = threadIdx.x & 31, ty = threadIdx.x >> 5;
#pragma unroll
  for (int j = 0; j < 32; j += 8) {
    tile[ty + j][tx] = x[((size_t)(n * CC + c0 + ty + j)) * 3200 + tv0 + tx];
  }
  __syncthreads();
#pragma unroll
  for (int j = 0; j < 32; j += 8) {
    int tv = tv0 + ty + j;
    int st = tv / CV, v = tv - st * CV;
    size_t row = ((size_t)n * TP + st + 1) * CV + v;
    xtp[row * CC + c0 + tx] = f2bf(tile[tx][ty + j]);
  }
}

// ---- zero the boundary frames (st = -1 and st = T) ----
__global__ __launch_bounds__(256) void k_zero_pad(unsigned short* __restrict__ xtp) {
  int i = blockIdx.x * 256 + threadIdx.x;  // 400*256 = 102400 exact
  int c = i & 255;
  int rid = i >> 8;  // [0,400)
  int n = rid / 50;
  int rem = rid - n * 50;
  int side = rem / 25;
  int v = rem - side * 25;
  size_t row = ((size_t)n * TP + side * (TP - 1)) * CV + v;
  xtp[row * CC + c] = 0;
}

// ---- LayerNorm over rows of 256 ----
__global__ __launch_bounds__(256) void k_ln(const unsigned short* __restrict__ X,
                                            const float* __restrict__ g,
                                            const float* __restrict__ b,
                                            unsigned short* __restrict__ Y) {
  const int r = blockIdx.x;
  const int c = threadIdx.x;
  float xv = bf2f(X[(size_t)r * CC + c]);
  float s = xv, q = xv * xv;
#pragma unroll
  for (int o = 32; o; o >>= 1) { s += __shfl_down(s, o); q += __shfl_down(q, o); }
  __shared__ float ls[8];
  const int wid = c >> 6, ln = c & 63;
  if (ln == 0) { ls[wid] = s; ls[4 + wid] = q; }
  __syncthreads();
  s = ls[0] + ls[1] + ls[2] + ls[3];
  q = ls[4] + ls[5] + ls[6] + ls[7];
  const float mean = s * (1.f / CC);
  const float var = q * (1.f / CC) - mean * mean;
  const float rs = rsqrtf(var + 1e-5f);
  Y[(size_t)r * CC + c] = f2bf((xv - mean) * rs * g[c] + b[c]);
}

// ---- generic 64x64x16-tiled fp32 GEMM, K=N=256, bf16 A / f32 B, bf16 out ----
// AMODE: 0 direct rows of A; 2 gather(A)[arow(r)] * scaleVec[b(r),k];
//        3 A[r] + gather(A2)[arow(r)]
// EPI:   0 bias only; 1 gelu(acc+bias); 2 +addSrc[r]; 3 +addSrc[arow(r)]
template <int AMODE, int EPI>
__global__ __launch_bounds__(256) void k_gemm(const unsigned short* __restrict__ A,
                                              const unsigned short* __restrict__ A2,
                                              const float* __restrict__ scaleVec,
                                              const float* __restrict__ Bw,
                                              const float* __restrict__ bias,
                                              const unsigned short* __restrict__ addSrc,
                                              unsigned short* __restrict__ Cout,
                                              int M) {
  __shared__ float As[16 * 68];
  __shared__ float Bs[16 * 68];
  const int tid = threadIdx.x;
  const int tx = tid & 15, ty = tid >> 4;
  const int r0 = blockIdx.x * 64;
  const int n0 = blockIdx.y * 64;
  float acc[4][4] = {};
  for (int k0 = 0; k0 < CC; k0 += 16) {
#pragma unroll
    for (int pp = 0; pp < 2; ++pp) {
      const int p = tid + pp * 256;
      const int m = p >> 3;
      const int kp = (p & 7) * 2;
      const int r = r0 + m;
      float v0 = 0.f, v1 = 0.f;
      if (r < M) {
        if (AMODE == 0) {
          unsigned u = *(const unsigned*)(A + (size_t)r * CC + k0 + kp);
          v0 = bf2f_lo(u);
          v1 = bf2f_hi(u);
        } else if (AMODE == 2) {
          const int ar = arow(r);
          const int bb = r / CL;
          unsigned u = *(const unsigned*)(A + (size_t)ar * CC + k0 + kp);
          v0 = bf2f_lo(u) * scaleVec[bb * CC + k0 + kp];
          v1 = bf2f_hi(u) * scaleVec[bb * CC + k0 + kp + 1];
        } else {  // 3
          const int ar = arow(r);
          unsigned u1 = *(const unsigned*)(A + (size_t)r * CC + k0 + kp);
          unsigned u2 = *(const unsigned*)(A2 + (size_t)ar * CC + k0 + kp);
          v0 = bf2f_lo(u1) + bf2f_lo(u2);
          v1 = bf2f_hi(u1) + bf2f_hi(u2);
        }
      }
      As[kp * 68 + m] = v0;
      As[(kp + 1) * 68 + m] = v1;
    }
    {
      const int kb = tid >> 4, c4 = (tid & 15) * 4;
      const float4 bv4 = *(const float4*)(Bw + (size_t)(k0 + kb) * CC + n0 + c4);
      Bs[kb * 68 + c4 + 0] = bv4.x;
      Bs[kb * 68 + c4 + 1] = bv4.y;
      Bs[kb * 68 + c4 + 2] = bv4.z;
      Bs[kb * 68 + c4 + 3] = bv4.w;
    }
    __syncthreads();
#pragma unroll
    for (int kk = 0; kk < 16; ++kk) {
      const float4 av = *(const float4*)&As[kk * 68 + ty * 4];
      const float4 bv = *(const float4*)&Bs[kk * 68 + tx * 4];
      const float a0[4] = {av.x, av.y, av.z, av.w};
      const float b0[4] = {bv.x, bv.y, bv.z, bv.w};
#pragma unroll
      for (int i = 0; i < 4; ++i)
#pragma unroll
        for (int j = 0; j < 4; ++j) acc[i][j] += a0[i] * b0[j];
    }
    __syncthreads();
  }
#pragma unroll
  for (int i = 0; i < 4; ++i) {
    const int r = r0 + ty * 4 + i;
    if (r >= M) continue;
    int ar3 = 0;
    if (EPI == 3) ar3 = arow(r);
#pragma unroll
    for (int j = 0; j < 4; j += 2) {
      const int col = n0 + tx * 4 + j;
      float v0 = acc[i][j] + bias[col];
      float v1 = acc[i][j + 1] + bias[col + 1];
      if (EPI == 1) {
        v0 = geluf(v0);
        v1 = geluf(v1);
      } else if (EPI == 2) {
        unsigned u = *(const unsigned*)(addSrc + (size_t)r * CC + col);
        v0 += bf2f_lo(u);
        v1 += bf2f_hi(u);
      } else if (EPI == 3) {
        unsigned u = *(const unsigned*)(addSrc + (size_t)ar3 * CC + col);
        v0 += bf2f_lo(u);
        v1 += bf2f_hi(u);
      }
      *(unsigned*)(Cout + (size_t)r * CC + col) = packbf(v0, v1);
    }
  }
}

// ---- rows x (256 -> 8) tiny projection. MODE 0: direct (QA); 1: gather*pq (KWL)
template <int MODE>
__global__ __launch_bounds__(256) void k_proj8(const unsigned short* __restrict__ SRC,
                                               const float* __restrict__ pq,
                                               const float* __restrict__ Wsm,
                                               const float* __restrict__ bsm,
                                               float* __restrict__ OUT) {
  const int r = blockIdx.x;
  const int c = threadIdx.x;
  float m;
  if (MODE == 0) {
    m = bf2f(SRC[(size_t)r * CC + c]);
  } else {
    const int ar = arow(r);
    const int bb = r / CL;
    m = bf2f(SRC[(size_t)ar * CC + c]) * pq[bb * CC + c];
  }
  float w8[8];
#pragma unroll
  for (int h = 0; h < 8; ++h) w8[h] = Wsm[c * 8 + h];
  __shared__ float ls[32];
  const int wid = c >> 6, ln = c & 63;
#pragma unroll
  for (int h = 0; h < 8; ++h) {
    float p = m * w8[h];
#pragma unroll
    for (int o = 32; o; o >>= 1) p += __shfl_down(p, o);
    if (ln == 0) ls[wid * 8 + h] = p;
  }
  __syncthreads();
  if (c < 8) {
    float sres = ls[c] + ls[8 + c] + ls[16 + c] + ls[24 + c] + bsm[c];
    if (MODE == 0)
      OUT[(size_t)r * 8 + c] = sres;
    else {
      const int bb = r / CL, l = r - bb * CL;
      OUT[((size_t)bb * 8 + c) * CL + l] = sres;
    }
  }
}

// ---- softmax over l (75) for each (b,h). MODE 0: gather from QA (26000,8); 1: in-place (B,H,L)
template <int MODE>
__global__ __launch_bounds__(128) void k_softmax(const float* __restrict__ SRC,
                                                 float* __restrict__ DST) {
  const int b = blockIdx.x;
  const int t = threadIdx.x;
  __shared__ float red[128];
  for (int h = 0; h < 8; ++h) {
    float v = -1e30f;
    if (t < CL) {
      if (MODE == 0) {
        const int ar = arow(b * CL + t);
        v = SRC[(size_t)ar * 8 + h] * SM_SCALE;
      } else {
        v = SRC[((size_t)b * 8 + h) * CL + t] * SM_SCALE;
      }
    }
    red[t] = v;
    __syncthreads();
    for (int s2 = 64; s2; s2 >>= 1) {
      if (t < s2) red[t] = fmaxf(red[t], red[t + s2]);
      __syncthreads();
    }
    const float mx = red[0];
    __syncthreads();
    const float e = (t < CL) ? __expf(v - mx) : 0.f;
    red[t] = e;
    __syncthreads();
    for (int s2 = 64; s2; s2 >>= 1) {
      if (t < s2) red[t] += red[t + s2];
      __syncthreads();
    }
    const float inv = 1.f / red[0];
    __syncthreads();
    if (t < CL) DST[((size_t)b * 8 + h) * CL + t] = e * inv;
    __syncthreads();
  }
}

// ---- pooled vector: OUT[b,c] = sum_l WGT[b, c>>5, l] * SRC[arow(b,l), c] ----
__global__ __launch_bounds__(256) void k_pool(const float* __restrict__ WGT,
                                              const unsigned short* __restrict__ SRC,
                                              float* __restrict__ OUT) {
  const int b = blockIdx.x;
  const int c = threadIdx.x;
  __shared__ int ar[CL];
  __shared__ float wg[8 * CL];
  if (c < CL) ar[c] = arow(b * CL + c);
  for (int i = c; i < 8 * CL; i += 256) wg[i] = WGT[(size_t)b * 8 * CL + i];
  __syncthreads();
  const int h = c >> 5;
  float acc = 0.f;
  for (int l = 0; l < CL; ++l) acc += wg[h * CL + l] * bf2f(SRC[(size_t)ar[l] * CC + c]);
  OUT[(size_t)b * CC + c] = acc;
}

// ---- final window contraction: out[n,o,t,v] = sum_{w,i} H[(b,w,v),i]*c2w[w,i,o]+c2b[o]
__global__ __launch_bounds__(256) void k_out(const unsigned short* __restrict__ H,
                                             const float* __restrict__ c2w,
                                             const float* __restrict__ c2b,
                                             float* __restrict__ out) {
  const int b = blockIdx.x;  // n*T + t
  const int o = threadIdx.x;
  const int n = b >> 7, t = b & 127;
  __shared__ float Hs[25 * 256];
  float acc[25];
  const float bias = c2b[o];
#pragma unroll
  for (int v = 0; v < 25; ++v) acc[v] = bias;
  for (int w = 0; w < 3; ++w) {
    __syncthreads();
    const unsigned* src = (const unsigned*)(H + ((size_t)b * CL + w * 25) * CC);
    for (int i = o; i < 25 * 256 / 2; i += 256) {
      unsigned u = src[i];
      Hs[2 * i] = bf2f_lo(u);
      Hs[2 * i + 1] = bf2f_hi(u);
    }
    __syncthreads();
    for (int i = 0; i < 256; ++i) {
      const float bw = c2w[((size_t)w * 256 + i) * 256 + o];
#pragma unroll
      for (int v = 0; v < 25; ++v) acc[v] += Hs[v * 256 + i] * bw;
    }
  }
  float* dst = out + ((size_t)(n * 256 + o) * CT + t) * CV;
#pragma unroll
  for (int v = 0; v < 25; ++v) dst[v] = acc[v];
}

extern "C" void kernel_launch(void* const* d_in, const int* in_sizes, int n_in,
                              void* d_out, int out_size, void* d_ws, size_t ws_size,
                              hipStream_t stream) {
  const float* x = (const float*)d_in[0];
  const float* ln1_g = (const float*)d_in[1];
  const float* ln1_b = (const float*)d_in[2];
  const float* Wq = (const float*)d_in[3];
  const float* bq = (const float*)d_in[4];
  const float* Wqa = (const float*)d_in[5];
  const float* bqa = (const float*)d_in[6];
  const float* Wk = (const float*)d_in[7];
  const float* bk = (const float*)d_in[8];
  const float* Wka = (const float*)d_in[9];
  const float* bka = (const float*)d_in[10];
  const float* Wv = (const float*)d_in[11];
  const float* bv = (const float*)d_in[12];
  const float* Wt = (const float*)d_in[13];
  const float* bt = (const float*)d_in[14];
  const float* Wp = (const float*)d_in[15];
  const float* bp = (const float*)d_in[16];
  const float* ffn_g = (const float*)d_in[17];
  const float* ffn_b = (const float*)d_in[18];
  const float* W1 = (const float*)d_in[19];
  const float* b1 = (const float*)d_in[20];
  const float* W2 = (const float*)d_in[21];
  const float* b2 = (const float*)d_in[22];
  const float* tn_g = (const float*)d_in[23];
  const float* tn_b = (const float*)d_in[24];
  const float* c1w = (const float*)d_in[25];
  const float* c1b = (const float*)d_in[26];
  const float* c2w = (const float*)d_in[27];
  const float* c2b = (const float*)d_in[28];
  float* out = (float*)d_out;

  char* wp = (char*)d_ws;
  auto alloc = [&](size_t bytes) -> char* {
    char* p = wp;
    wp += (bytes + 255) & ~(size_t)255;
    return p;
  };
  unsigned short* XTP = (unsigned short*)alloc((size_t)MPAD * CC * 2);
  unsigned short* LNXP = (unsigned short*)alloc((size_t)MPAD * CC * 2);
  unsigned short* QP = (unsigned short*)alloc((size_t)MPAD * CC * 2);
  unsigned short* KP = (unsigned short*)alloc((size_t)MPAD * CC * 2);
  unsigned short* VP = (unsigned short*)alloc((size_t)MPAD * CC * 2);
  unsigned short* KVb = (unsigned short*)alloc((size_t)MBL * CC * 2);  // KV -> F -> TN
  unsigned short* ATTb = (unsigned short*)alloc((size_t)MBL * CC * 2); // ATT -> H
  unsigned short* Gb = (unsigned short*)alloc((size_t)MBL * CC * 2);
  unsigned short* Yb = (unsigned short*)alloc((size_t)MBL * CC * 2);
  float* QA = (float*)alloc((size_t)MPAD * 8 * 4);
  float* QW = (float*)alloc((size_t)1024 * 8 * CL * 4);
  float* KWL = (float*)alloc((size_t)1024 * 8 * CL * 4);
  float* PQ = (float*)alloc((size_t)1024 * CC * 4);
  float* PK = (float*)alloc((size_t)1024 * CC * 4);

  k_transpose<<<dim3(8, 100, 8), 256, 0, stream>>>(x, XTP);
  k_zero_pad<<<400, 256, 0, stream>>>(XTP);
  k_ln<<<MPAD, 256, 0, stream>>>(XTP, ln1_g, ln1_b, LNXP);

  const dim3 gP((MPAD + 63) / 64, 4);
  const dim3 gB(MBL / 64, 4);
  k_gemm<0, 0><<<gP, 256, 0, stream>>>(LNXP, nullptr, nullptr, Wq, bq, nullptr, QP, MPAD);
  k_gemm<0, 0><<<gP, 256, 0, stream>>>(LNXP, nullptr, nullptr, Wk, bk, nullptr, KP, MPAD);
  k_gemm<0, 0><<<gP, 256, 0, stream>>>(LNXP, nullptr, nullptr, Wv, bv, nullptr, VP, MPAD);

  k_proj8<0><<<MPAD, 256, 0, stream>>>(QP, nullptr, Wqa, bqa, QA);
  k_softmax<0><<<1024, 128, 0, stream>>>(QA, QW);
  k_pool<<<1024, 256, 0, stream>>>(QW, QP, PQ);

  k_proj8<1><<<MBL, 256, 0, stream>>>(KP, PQ, Wka, bka, KWL);
  k_softmax<1><<<1024, 128, 0, stream>>>(KWL, KWL);
  k_pool<<<1024, 256, 0, stream>>>(KWL, KP, PK);

  k_gemm<2, 0><<<gB, 256, 0, stream>>>(VP, nullptr, PK, Wt, bt, nullptr, KVb, MBL);
  k_gemm<3, 3><<<gB, 256, 0, stream>>>(KVb, QP, nullptr, Wp, bp, XTP, ATTb, MBL);

  k_ln<<<MBL, 256, 0, stream>>>(ATTb, ffn_g, ffn_b, KVb);                           // F
  k_gemm<0, 1><<<gB, 256, 0, stream>>>(KVb, nullptr, nullptr, W1, b1, nullptr, Gb, MBL);
  k_gemm<0, 2><<<gB, 256, 0, stream>>>(Gb, nullptr, nullptr, W2, b2, ATTb, Yb, MBL);

  k_ln<<<MBL, 256, 0, stream>>>(Yb, tn_g, tn_b, KVb);                               // TN
  k_gemm<0, 1><<<gB, 256, 0, stream>>>(KVb, nullptr, nullptr, c1w, c1b, nullptr, ATTb, MBL); // H

  k_out<<<1024, 256, 0, stream>>>(ATTb, c2w, c2b, out);
}

// Round 5
// 582.848 us; speedup vs baseline: 2.6944x; 2.6944x over previous
//
#include <hip/hip_runtime.h>

// ---------------------------------------------------------------------------
// Pipeline (intermediates bf16, f32 accum; all big GEMMs on MFMA bf16):
//   x (N,C,T,V) f32 --transpose--> XTP (N,T+2,V,C) bf16 (boundary frames = 0)
//   LNXP = LN(XTP, ln1)                  [26000 rows; 3x dedup vs (B,L)]
//   QP/KP/VP = LNXP @ W{q,k,v} + b       [MFMA]
//   QA -> softmax -> QW; PQ pool; KWL -> softmax -> KW; PK pool
//   KV  = (gather(VP) * PK_b) @ Wt + bt              [MFMA, fused gather+scale]
//   ATT = (KVb + gather(QP)) @ Wp + bp + gather(XTP) [MFMA, fused]
//   F = LN(ATT); G = gelu(F@W1+b1); Y = G@W2+b2+ATT  [MFMA]
//   TN = LN(Y);  H = gelu(TN@c1w+c1b)                [MFMA]
//   out = H-window-contraction @ c2w + c2b           [MFMA, K=768, transposed
//                                                     f32 store to (N,O,T,V)]
// ---------------------------------------------------------------------------

#define DI __device__ __forceinline__

constexpr int CC   = 256;
constexpr int CL   = 75;
constexpr int CV   = 25;
constexpr int CT   = 128;
constexpr int TP   = 130;          // T+2 padded frames
constexpr int MPAD = 8 * TP * CV;  // 26000
constexpr int MBL  = 1024 * CL;    // 76800
constexpr int MOUT = 8 * CT * CV;  // 25600
constexpr float SM_SCALE = 0.17677669529663687f;  // 1/sqrt(32)

typedef __bf16 bf16x8 __attribute__((ext_vector_type(8)));
typedef float f32x4 __attribute__((ext_vector_type(4)));

DI float bf2f(unsigned short u) { return __uint_as_float(((unsigned)u) << 16); }
DI float bf2f_lo(unsigned u) { return __uint_as_float(u << 16); }
DI float bf2f_hi(unsigned u) { return __uint_as_float(u & 0xffff0000u); }
DI unsigned short f2bf(float f) {
  unsigned u = __float_as_uint(f);
  u += 0x7fffu + ((u >> 16) & 1u);
  return (unsigned short)(u >> 16);
}
DI unsigned packbf(float a, float b) {
  return (unsigned)f2bf(a) | ((unsigned)f2bf(b) << 16);
}
DI float geluf(float x) { return 0.5f * x * (1.f + erff(x * 0.70710678118654752440f)); }

// (B,L) row -> padded-frame row: r=(b,l), b=n*128+t, l=w*25+v -> (n*130+t+w)*25+v
DI int arow(int r) {
  int b = r / CL;
  int l = r - b * CL;
  int w = l / CV;
  int v = l - w * CV;
  int t = b & (CT - 1);
  int n = b >> 7;
  return (n * TP + t + w) * CV + v;
}

// ---- x (N,C,T,V) f32 -> XTP (N,T+2,V,C) bf16, interior frames ----
__global__ __launch_bounds__(256) void k_transpose(const float* __restrict__ x,
                                                   unsigned short* __restrict__ xtp) {
  __shared__ float tile[32][33];
  const int n = blockIdx.z;
  const int c0 = blockIdx.x * 32;
  const int tv0 = blockIdx.y * 32;
  const int tx = threadIdx.x & 31, ty = threadIdx.x >> 5;
#pragma unroll
  for (int j = 0; j < 32; j += 8) {
    tile[ty + j][tx] = x[((size_t)(n * CC + c0 + ty + j)) * 3200 + tv0 + tx];
  }
  __syncthreads();
#pragma unroll
  for (int j = 0; j < 32; j += 8) {
    int tv = tv0 + ty + j;
    int st = tv / CV, v = tv - st * CV;
    size_t row = ((size_t)n * TP + st + 1) * CV + v;
    xtp[row * CC + c0 + tx] = f2bf(tile[tx][ty + j]);
  }
}

// ---- zero the boundary frames (st = -1 and st = T) ----
__global__ __launch_bounds__(256) void k_zero_pad(unsigned short* __restrict__ xtp) {
  int i = blockIdx.x * 256 + threadIdx.x;  // 400*256 = 102400 exact
  int c = i & 255;
  int rid = i >> 8;
  int n = rid / 50;
  int rem = rid - n * 50;
  int side = rem / 25;
  int v = rem - side * 25;
  size_t row = ((size_t)n * TP + side * (TP - 1)) * CV + v;
  xtp[row * CC + c] = 0;
}

// ---- weight transpose+convert: dst[n*stride + off + k] = f2bf(src[k*256+n]) ----
struct TJobs {
  const float* src[11];
  unsigned short* dst[11];
  int stride[11];
  int off[11];
};
__global__ __launch_bounds__(256) void k_wtrans(TJobs J) {
  __shared__ float tile[32][33];
  const int j = blockIdx.z;
  const float* src = J.src[j];
  unsigned short* dst = J.dst[j];
  const int stride = J.stride[j], off = J.off[j];
  const int k0 = blockIdx.x * 32, n0 = blockIdx.y * 32;
  const int tx = threadIdx.x & 31, ty = threadIdx.x >> 5;
#pragma unroll
  for (int jj = 0; jj < 32; jj += 8)
    tile[ty + jj][tx] = src[(size_t)(k0 + ty + jj) * 256 + n0 + tx];
  __syncthreads();
#pragma unroll
  for (int jj = 0; jj < 32; jj += 8)
    dst[(size_t)(n0 + ty + jj) * stride + off + k0 + tx] = f2bf(tile[tx][ty + jj]);
}

// ---- LayerNorm: one wave per row, 4 rows per block ----
__global__ __launch_bounds__(256) void k_ln4(const unsigned short* __restrict__ X,
                                             const float* __restrict__ g,
                                             const float* __restrict__ b,
                                             unsigned short* __restrict__ Y) {
  const int row = blockIdx.x * 4 + (threadIdx.x >> 6);
  const int lane = threadIdx.x & 63;
  const uint2 u = *(const uint2*)(X + (size_t)row * CC + lane * 4);
  const float x0 = bf2f_lo(u.x), x1 = bf2f_hi(u.x), x2 = bf2f_lo(u.y), x3 = bf2f_hi(u.y);
  float s = x0 + x1 + x2 + x3;
  float q = x0 * x0 + x1 * x1 + x2 * x2 + x3 * x3;
#pragma unroll
  for (int o = 32; o; o >>= 1) { s += __shfl_xor(s, o); q += __shfl_xor(q, o); }
  const float mean = s * (1.f / CC);
  const float var = q * (1.f / CC) - mean * mean;
  const float rs = rsqrtf(var + 1e-5f);
  const float4 g4 = *(const float4*)(g + lane * 4);
  const float4 b4 = *(const float4*)(b + lane * 4);
  uint2 o2;
  o2.x = packbf((x0 - mean) * rs * g4.x + b4.x, (x1 - mean) * rs * g4.y + b4.y);
  o2.y = packbf((x2 - mean) * rs * g4.z + b4.z, (x3 - mean) * rs * g4.w + b4.w);
  *(uint2*)(Y + (size_t)row * CC + lane * 4) = o2;
}

// ---- A-operand 16B loader for the MFMA GEMM ----
// AMODE 0: direct; 2: gather*scale; 3: A[r]+gather(A2); 4: H window gather (K=768)
template <int AMODE>
DI uint4 load_a16(const unsigned short* __restrict__ A, const unsigned short* __restrict__ A2,
                  const float* __restrict__ scaleVec, int r, int kg) {
  if constexpr (AMODE == 0) {
    return *(const uint4*)(A + (size_t)r * CC + kg);
  } else if constexpr (AMODE == 2) {
    const int ar = arow(r), bb = r / CL;
    const uint4 u = *(const uint4*)(A + (size_t)ar * CC + kg);
    const float* sv = scaleVec + bb * CC + kg;
    const float4 s0 = *(const float4*)(sv);
    const float4 s1 = *(const float4*)(sv + 4);
    uint4 o;
    o.x = packbf(bf2f_lo(u.x) * s0.x, bf2f_hi(u.x) * s0.y);
    o.y = packbf(bf2f_lo(u.y) * s0.z, bf2f_hi(u.y) * s0.w);
    o.z = packbf(bf2f_lo(u.z) * s1.x, bf2f_hi(u.z) * s1.y);
    o.w = packbf(bf2f_lo(u.w) * s1.z, bf2f_hi(u.w) * s1.w);
    return o;
  } else if constexpr (AMODE == 3) {
    const int ar = arow(r);
    const uint4 u1 = *(const uint4*)(A + (size_t)r * CC + kg);
    const uint4 u2 = *(const uint4*)(A2 + (size_t)ar * CC + kg);
    uint4 o;
    o.x = packbf(bf2f_lo(u1.x) + bf2f_lo(u2.x), bf2f_hi(u1.x) + bf2f_hi(u2.x));
    o.y = packbf(bf2f_lo(u1.y) + bf2f_lo(u2.y), bf2f_hi(u1.y) + bf2f_hi(u2.y));
    o.z = packbf(bf2f_lo(u1.z) + bf2f_lo(u2.z), bf2f_hi(u1.z) + bf2f_hi(u2.z));
    o.w = packbf(bf2f_lo(u1.w) + bf2f_lo(u2.w), bf2f_hi(u1.w) + bf2f_hi(u2.w));
    return o;
  } else {  // AMODE 4: r = n*3200 + t*25 + v; k = w*256 + i -> H[(n*128+t)*75 + w*25 + v][i]
    const int n = r / 3200, rr = r - n * 3200;
    const int t = rr / 25, v = rr - t * 25;
    const int w = kg >> 8, kk = kg & 255;
    const int hr = (n * CT + t) * CL + w * CV + v;
    return *(const uint4*)(A + (size_t)hr * CC + kk);
  }
}

// ---- MFMA bf16 GEMM: BM=128, BN=256, BK=32, 512 threads (8 waves, 2x4) ----
// EPI: 0 bias; 1 gelu(acc+bias); 2 +addSrc[r]; 3 +addSrc[arow(r)];
//      4 f32 transposed store out[n*819200 + col*3200 + (r%3200)] (+bias)
template <int AMODE, int EPI>
__global__ __launch_bounds__(512) void k_mgemm(const unsigned short* __restrict__ A,
                                               const unsigned short* __restrict__ A2,
                                               const float* __restrict__ scaleVec,
                                               const unsigned short* __restrict__ BwT,
                                               const float* __restrict__ bias,
                                               const unsigned short* __restrict__ addSrc,
                                               unsigned short* __restrict__ Cout,
                                               float* __restrict__ FOut,
                                               int M, int KDIM) {
  __shared__ unsigned short As[128 * 32];
  __shared__ unsigned short Bs[256 * 32];
  const int tid = threadIdx.x;
  const int lane = tid & 63;
  const int wid = tid >> 6;
  const int wm = wid >> 2, wn = wid & 3;
  const int r0 = blockIdx.x * 128;
  f32x4 acc[4][4] = {};

  const int sm = tid >> 2, sseg = tid & 3;  // A staging: row, 8-elem segment

  for (int k0 = 0; k0 < KDIM; k0 += 32) {
    {  // stage A (128 x 32)
      const int r = r0 + sm;
      uint4 u = make_uint4(0, 0, 0, 0);
      if (r < M) u = load_a16<AMODE>(A, A2, scaleVec, r, k0 + sseg * 8);
      *(uint4*)(As + sm * 32 + sseg * 8) = u;
    }
#pragma unroll
    for (int pp = 0; pp < 2; ++pp) {  // stage B^T (256 x 32)
      const int s = tid + pp * 512;
      const int n = s >> 2, seg = s & 3;
      const uint4 u = *(const uint4*)(BwT + (size_t)n * KDIM + k0 + seg * 8);
      *(uint4*)(Bs + n * 32 + seg * 8) = u;
    }
    __syncthreads();
    bf16x8 af[4], bfrag[4];
#pragma unroll
    for (int mi = 0; mi < 4; ++mi)
      af[mi] = *(const bf16x8*)(As + (wm * 64 + mi * 16 + (lane & 15)) * 32 + (lane >> 4) * 8);
#pragma unroll
    for (int ni = 0; ni < 4; ++ni)
      bfrag[ni] = *(const bf16x8*)(Bs + (wn * 64 + ni * 16 + (lane & 15)) * 32 + (lane >> 4) * 8);
#pragma unroll
    for (int mi = 0; mi < 4; ++mi)
#pragma unroll
      for (int ni = 0; ni < 4; ++ni)
        acc[mi][ni] = __builtin_amdgcn_mfma_f32_16x16x32_bf16(af[mi], bfrag[ni], acc[mi][ni], 0, 0, 0);
    __syncthreads();
  }

  const int ln15 = lane & 15, lq = lane >> 4;
#pragma unroll
  for (int mi = 0; mi < 4; ++mi) {
#pragma unroll
    for (int ni = 0; ni < 4; ++ni) {
      const int col = wn * 64 + ni * 16 + ln15;
      const float bcol = bias[col];
#pragma unroll
      for (int rg = 0; rg < 4; ++rg) {
        const int r = r0 + wm * 64 + mi * 16 + lq * 4 + rg;
        if (r >= M) continue;
        float v = acc[mi][ni][rg] + bcol;
        if (EPI == 1) v = geluf(v);
        else if (EPI == 2) v += bf2f(addSrc[(size_t)r * CC + col]);
        else if (EPI == 3) v += bf2f(addSrc[(size_t)arow(r) * CC + col]);
        if (EPI == 4) {
          const int n = r / 3200, rr = r - n * 3200;
          FOut[(size_t)n * 819200 + (size_t)col * 3200 + rr] = v;
        } else {
          Cout[(size_t)r * CC + col] = f2bf(v);
        }
      }
    }
  }
}

// ---- rows x (256 -> 8) projection, one wave per row, 4 rows/block ----
// MODE 0: direct (QA, out [r][8]); 1: gather*pq (KWL, out [b][8][75])
template <int MODE>
__global__ __launch_bounds__(256) void k_proj8(const unsigned short* __restrict__ SRC,
                                               const float* __restrict__ pq,
                                               const float* __restrict__ Wsm,
                                               const float* __restrict__ bsm,
                                               float* __restrict__ OUT) {
  const int r = blockIdx.x * 4 + (threadIdx.x >> 6);
  const int lane = threadIdx.x & 63;
  const int c = lane * 4;
  float m0, m1, m2, m3;
  if (MODE == 0) {
    const uint2 u = *(const uint2*)(SRC + (size_t)r * CC + c);
    m0 = bf2f_lo(u.x); m1 = bf2f_hi(u.x); m2 = bf2f_lo(u.y); m3 = bf2f_hi(u.y);
  } else {
    const int ar = arow(r), bb = r / CL;
    const uint2 u = *(const uint2*)(SRC + (size_t)ar * CC + c);
    const float4 s4 = *(const float4*)(pq + bb * CC + c);
    m0 = bf2f_lo(u.x) * s4.x; m1 = bf2f_hi(u.x) * s4.y;
    m2 = bf2f_lo(u.y) * s4.z; m3 = bf2f_hi(u.y) * s4.w;
  }
  float p[8] = {};
#pragma unroll
  for (int j = 0; j < 4; ++j) {
    const float mj = (j == 0) ? m0 : (j == 1) ? m1 : (j == 2) ? m2 : m3;
#pragma unroll
    for (int h = 0; h < 8; ++h) p[h] += mj * Wsm[(c + j) * 8 + h];
  }
#pragma unroll
  for (int h = 0; h < 8; ++h) {
#pragma unroll
    for (int o = 32; o; o >>= 1) p[h] += __shfl_down(p[h], o);
  }
  if (lane == 0) {
    if (MODE == 0) {
#pragma unroll
      for (int h = 0; h < 8; ++h) OUT[(size_t)r * 8 + h] = p[h] + bsm[h];
    } else {
      const int bb = r / CL, l = r - bb * CL;
#pragma unroll
      for (int h = 0; h < 8; ++h) OUT[((size_t)bb * 8 + h) * CL + l] = p[h] + bsm[h];
    }
  }
}

// ---- softmax over l (75). MODE 0: gather from QA (26000,8); 1: in-place (B,H,L)
template <int MODE>
__global__ __launch_bounds__(128) void k_softmax(const float* __restrict__ SRC,
                                                 float* __restrict__ DST) {
  const int b = blockIdx.x;
  const int t = threadIdx.x;
  __shared__ float red[128];
  for (int h = 0; h < 8; ++h) {
    float v = -1e30f;
    if (t < CL) {
      if (MODE == 0) {
        const int ar = arow(b * CL + t);
        v = SRC[(size_t)ar * 8 + h] * SM_SCALE;
      } else {
        v = SRC[((size_t)b * 8 + h) * CL + t] * SM_SCALE;
      }
    }
    red[t] = v;
    __syncthreads();
    for (int s2 = 64; s2; s2 >>= 1) {
      if (t < s2) red[t] = fmaxf(red[t], red[t + s2]);
      __syncthreads();
    }
    const float mx = red[0];
    __syncthreads();
    const float e = (t < CL) ? __expf(v - mx) : 0.f;
    red[t] = e;
    __syncthreads();
    for (int s2 = 64; s2; s2 >>= 1) {
      if (t < s2) red[t] += red[t + s2];
      __syncthreads();
    }
    const float inv = 1.f / red[0];
    __syncthreads();
    if (t < CL) DST[((size_t)b * 8 + h) * CL + t] = e * inv;
    __syncthreads();
  }
}

// ---- pooled vector: OUT[b,c] = sum_l WGT[b, c>>5, l] * SRC[arow(b,l), c] ----
__global__ __launch_bounds__(256) void k_pool(const float* __restrict__ WGT,
                                              const unsigned short* __restrict__ SRC,
                                              float* __restrict__ OUT) {
  const int b = blockIdx.x;
  const int c = threadIdx.x;
  __shared__ int ar[CL];
  __shared__ float wg[8 * CL];
  if (c < CL) ar[c] = arow(b * CL + c);
  for (int i = c; i < 8 * CL; i += 256) wg[i] = WGT[(size_t)b * 8 * CL + i];
  __syncthreads();
  const int h = c >> 5;
  float acc = 0.f;
  for (int l = 0; l < CL; ++l) acc += wg[h * CL + l] * bf2f(SRC[(size_t)ar[l] * CC + c]);
  OUT[(size_t)b * CC + c] = acc;
}

extern "C" void kernel_launch(void* const* d_in, const int* in_sizes, int n_in,
                              void* d_out, int out_size, void* d_ws, size_t ws_size,
                              hipStream_t stream) {
  const float* x = (const float*)d_in[0];
  const float* ln1_g = (const float*)d_in[1];
  const float* ln1_b = (const float*)d_in[2];
  const float* Wq = (const float*)d_in[3];
  const float* bq = (const float*)d_in[4];
  const float* Wqa = (const float*)d_in[5];
  const float* bqa = (const float*)d_in[6];
  const float* Wk = (const float*)d_in[7];
  const float* bk = (const float*)d_in[8];
  const float* Wka = (const float*)d_in[9];
  const float* bka = (const float*)d_in[10];
  const float* Wv = (const float*)d_in[11];
  const float* bv = (const float*)d_in[12];
  const float* Wt = (const float*)d_in[13];
  const float* bt = (const float*)d_in[14];
  const float* Wp = (const float*)d_in[15];
  const float* bp = (const float*)d_in[16];
  const float* ffn_g = (const float*)d_in[17];
  const float* ffn_b = (const float*)d_in[18];
  const float* W1 = (const float*)d_in[19];
  const float* b1 = (const float*)d_in[20];
  const float* W2 = (const float*)d_in[21];
  const float* b2 = (const float*)d_in[22];
  const float* tn_g = (const float*)d_in[23];
  const float* tn_b = (const float*)d_in[24];
  const float* c1w = (const float*)d_in[25];
  const float* c1b = (const float*)d_in[26];
  const float* c2w = (const float*)d_in[27];
  const float* c2b = (const float*)d_in[28];
  float* out = (float*)d_out;

  char* wp = (char*)d_ws;
  auto alloc = [&](size_t bytes) -> char* {
    char* p = wp;
    wp += (bytes + 255) & ~(size_t)255;
    return p;
  };
  unsigned short* XTP = (unsigned short*)alloc((size_t)MPAD * CC * 2);
  unsigned short* LNXP = (unsigned short*)alloc((size_t)MPAD * CC * 2);
  unsigned short* QP = (unsigned short*)alloc((size_t)MPAD * CC * 2);
  unsigned short* KP = (unsigned short*)alloc((size_t)MPAD * CC * 2);
  unsigned short* VP = (unsigned short*)alloc((size_t)MPAD * CC * 2);
  unsigned short* KVb = (unsigned short*)alloc((size_t)MBL * CC * 2);   // KV -> F -> TN
  unsigned short* ATTb = (unsigned short*)alloc((size_t)MBL * CC * 2);  // ATT -> H
  unsigned short* Gb = (unsigned short*)alloc((size_t)MBL * CC * 2);
  unsigned short* Yb = (unsigned short*)alloc((size_t)MBL * CC * 2);
  float* QA = (float*)alloc((size_t)MPAD * 8 * 4);
  float* QW = (float*)alloc((size_t)1024 * 8 * CL * 4);
  float* KWL = (float*)alloc((size_t)1024 * 8 * CL * 4);
  float* PQ = (float*)alloc((size_t)1024 * CC * 4);
  float* PK = (float*)alloc((size_t)1024 * CC * 4);
  unsigned short* WqT = (unsigned short*)alloc(256 * 256 * 2);
  unsigned short* WkT = (unsigned short*)alloc(256 * 256 * 2);
  unsigned short* WvT = (unsigned short*)alloc(256 * 256 * 2);
  unsigned short* WtT = (unsigned short*)alloc(256 * 256 * 2);
  unsigned short* WpT = (unsigned short*)alloc(256 * 256 * 2);
  unsigned short* W1T = (unsigned short*)alloc(256 * 256 * 2);
  unsigned short* W2T = (unsigned short*)alloc(256 * 256 * 2);
  unsigned short* c1wT = (unsigned short*)alloc(256 * 256 * 2);
  unsigned short* c2wT = (unsigned short*)alloc(256 * 768 * 2);

  // weight prep: dst[n][k] = bf16(src[k][n])
  TJobs J;
  const float* srcs[11] = {Wq, Wk, Wv, Wt, Wp, W1, W2, c1w, c2w, c2w + 65536, c2w + 131072};
  unsigned short* dsts[11] = {WqT, WkT, WvT, WtT, WpT, W1T, W2T, c1wT, c2wT, c2wT, c2wT};
  const int strides[11] = {256, 256, 256, 256, 256, 256, 256, 256, 768, 768, 768};
  const int offs[11] = {0, 0, 0, 0, 0, 0, 0, 0, 0, 256, 512};
  for (int i = 0; i < 11; ++i) {
    J.src[i] = srcs[i]; J.dst[i] = dsts[i]; J.stride[i] = strides[i]; J.off[i] = offs[i];
  }
  k_wtrans<<<dim3(8, 8, 11), 256, 0, stream>>>(J);

  k_transpose<<<dim3(8, 100, 8), 256, 0, stream>>>(x, XTP);
  k_zero_pad<<<400, 256, 0, stream>>>(XTP);
  k_ln4<<<MPAD / 4, 256, 0, stream>>>(XTP, ln1_g, ln1_b, LNXP);

  const int gP = (MPAD + 127) / 128;  // 204
  const int gB = MBL / 128;           // 600
  k_mgemm<0, 0><<<gP, 512, 0, stream>>>(LNXP, nullptr, nullptr, WqT, bq, nullptr, QP, nullptr, MPAD, 256);
  k_mgemm<0, 0><<<gP, 512, 0, stream>>>(LNXP, nullptr, nullptr, WkT, bk, nullptr, KP, nullptr, MPAD, 256);
  k_mgemm<0, 0><<<gP, 512, 0, stream>>>(LNXP, nullptr, nullptr, WvT, bv, nullptr, VP, nullptr, MPAD, 256);

  k_proj8<0><<<MPAD / 4, 256, 0, stream>>>(QP, nullptr, Wqa, bqa, QA);
  k_softmax<0><<<1024, 128, 0, stream>>>(QA, QW);
  k_pool<<<1024, 256, 0, stream>>>(QW, QP, PQ);

  k_proj8<1><<<MBL / 4, 256, 0, stream>>>(KP, PQ, Wka, bka, KWL);
  k_softmax<1><<<1024, 128, 0, stream>>>(KWL, KWL);
  k_pool<<<1024, 256, 0, stream>>>(KWL, KP, PK);

  k_mgemm<2, 0><<<gB, 512, 0, stream>>>(VP, nullptr, PK, WtT, bt, nullptr, KVb, nullptr, MBL, 256);
  k_mgemm<3, 3><<<gB, 512, 0, stream>>>(KVb, QP, nullptr, WpT, bp, XTP, ATTb, nullptr, MBL, 256);

  k_ln4<<<MBL / 4, 256, 0, stream>>>(ATTb, ffn_g, ffn_b, KVb);  // F
  k_mgemm<0, 1><<<gB, 512, 0, stream>>>(KVb, nullptr, nullptr, W1T, b1, nullptr, Gb, nullptr, MBL, 256);
  k_mgemm<0, 2><<<gB, 512, 0, stream>>>(Gb, nullptr, nullptr, W2T, b2, ATTb, Yb, nullptr, MBL, 256);

  k_ln4<<<MBL / 4, 256, 0, stream>>>(Yb, tn_g, tn_b, KVb);  // TN
  k_mgemm<0, 1><<<gB, 512, 0, stream>>>(KVb, nullptr, nullptr, c1wT, c1b, nullptr, ATTb, nullptr, MBL, 256);  // H

  k_mgemm<4, 4><<<MOUT / 128, 512, 0, stream>>>(ATTb, nullptr, nullptr, c2wT, c2b, nullptr, nullptr, out, MOUT, 768);
}

// Round 6
// 446.927 us; speedup vs baseline: 3.5138x; 1.3041x over previous
//
#include <hip/hip_runtime.h>

// ---------------------------------------------------------------------------
// Pipeline (intermediates bf16, f32 accum; all big GEMMs on pipelined MFMA):
//   x (N,C,T,V) f32 --transpose--> XTP (N,T+2,V,C) bf16 (boundary frames = 0)
//   LNXP = LN(XTP, ln1)                  [26000 rows; 3x dedup vs (B,L)]
//   QP/KP/VP = LNXP @ W{q,k,v} + b       [MFMA, global_load_lds both operands]
//   QA -> softmax -> QW; PQ pool; KWL -> softmax -> KW; PK pool
//   ATT = [VPg*pk | QPg] @ [[Wt*Wp];[Wp]] + (bt*Wp+bp) + XTPg   [MFMA K=512,
//         fuses the old Wt- and Wp-GEMMs; Wt*Wp precomputed per launch]
//   F = LN(ATT); G = gelu(F@W1+b1); Y = G@W2+b2+ATT  [MFMA]
//   TN = LN(Y);  H = gelu(TN@c1w+c1b)                [MFMA]
//   out = H-window-contraction @ c2w + c2b           [MFMA K=768, float4
//                                                     transposed store]
// GEMM structure: BM=64, BN=256, BK=32, 512 thr (8 waves 2x4, wave 32x64),
// double-buffered LDS, prefetch-issue before MFMA, 1 barrier per K-step.
// ---------------------------------------------------------------------------

#define DI __device__ __forceinline__

constexpr int CC   = 256;
constexpr int CL   = 75;
constexpr int CV   = 25;
constexpr int CT   = 128;
constexpr int TP   = 130;          // T+2 padded frames
constexpr int MPAD = 8 * TP * CV;  // 26000
constexpr int MBL  = 1024 * CL;    // 76800
constexpr int MOUT = 8 * CT * CV;  // 25600
constexpr float SM_SCALE = 0.17677669529663687f;  // 1/sqrt(32)

typedef __bf16 bf16x8 __attribute__((ext_vector_type(8)));
typedef float f32x4 __attribute__((ext_vector_type(4)));

DI float bf2f(unsigned short u) { return __uint_as_float(((unsigned)u) << 16); }
DI float bf2f_lo(unsigned u) { return __uint_as_float(u << 16); }
DI float bf2f_hi(unsigned u) { return __uint_as_float(u & 0xffff0000u); }
DI unsigned short f2bf(float f) {
  unsigned u = __float_as_uint(f);
  u += 0x7fffu + ((u >> 16) & 1u);
  return (unsigned short)(u >> 16);
}
DI unsigned packbf(float a, float b) {
  return (unsigned)f2bf(a) | ((unsigned)f2bf(b) << 16);
}
DI float geluf(float x) { return 0.5f * x * (1.f + erff(x * 0.70710678118654752440f)); }

// async global->LDS, 16B per lane (dest = wave-uniform base + lane*16)
DI void gll16(const unsigned short* g, unsigned short* l) {
  __builtin_amdgcn_global_load_lds(
      (const __attribute__((address_space(1))) unsigned int*)g,
      (__attribute__((address_space(3))) unsigned int*)l, 16, 0, 0);
}

// (B,L) row -> padded-frame row: r=(b,l), b=n*128+t, l=w*25+v -> (n*130+t+w)*25+v
DI int arow(int r) {
  int b = r / CL;
  int l = r - b * CL;
  int w = l / CV;
  int v = l - w * CV;
  int t = b & (CT - 1);
  int n = b >> 7;
  return (n * TP + t + w) * CV + v;
}

// ---- x (N,C,T,V) f32 -> XTP (N,T+2,V,C) bf16, interior frames ----
__global__ __launch_bounds__(256) void k_transpose(const float* __restrict__ x,
                                                   unsigned short* __restrict__ xtp) {
  __shared__ float tile[32][33];
  const int n = blockIdx.z;
  const int c0 = blockIdx.x * 32;
  const int tv0 = blockIdx.y * 32;
  const int tx = threadIdx.x & 31, ty = threadIdx.x >> 5;
#pragma unroll
  for (int j = 0; j < 32; j += 8) {
    tile[ty + j][tx] = x[((size_t)(n * CC + c0 + ty + j)) * 3200 + tv0 + tx];
  }
  __syncthreads();
#pragma unroll
  for (int j = 0; j < 32; j += 8) {
    int tv = tv0 + ty + j;
    int st = tv / CV, v = tv - st * CV;
    size_t row = ((size_t)n * TP + st + 1) * CV + v;
    xtp[row * CC + c0 + tx] = f2bf(tile[tx][ty + j]);
  }
}

// ---- zero the boundary frames (st = -1 and st = T) ----
__global__ __launch_bounds__(256) void k_zero_pad(unsigned short* __restrict__ xtp) {
  int i = blockIdx.x * 256 + threadIdx.x;  // 400*256 = 102400 exact
  int c = i & 255;
  int rid = i >> 8;
  int n = rid / 50;
  int rem = rid - n * 50;
  int side = rem / 25;
  int v = rem - side * 25;
  size_t row = ((size_t)n * TP + side * (TP - 1)) * CV + v;
  xtp[row * CC + c] = 0;
}

// ---- weight transpose+convert: dst[n*stride + off + k] = f2bf(src[k*256+n]) ----
struct TJobs {
  const float* src[10];
  unsigned short* dst[10];
  int stride[10];
  int off[10];
};
__global__ __launch_bounds__(256) void k_wtrans(TJobs J) {
  __shared__ float tile[32][33];
  const int j = blockIdx.z;
  const float* src = J.src[j];
  unsigned short* dst = J.dst[j];
  const int stride = J.stride[j], off = J.off[j];
  const int k0 = blockIdx.x * 32, n0 = blockIdx.y * 32;
  const int tx = threadIdx.x & 31, ty = threadIdx.x >> 5;
#pragma unroll
  for (int jj = 0; jj < 32; jj += 8)
    tile[ty + jj][tx] = src[(size_t)(k0 + ty + jj) * 256 + n0 + tx];
  __syncthreads();
#pragma unroll
  for (int jj = 0; jj < 32; jj += 8)
    dst[(size_t)(n0 + ty + jj) * stride + off + k0 + tx] = f2bf(tile[tx][ty + jj]);
}

// ---- WtWp[k][n] = sum_j Wt[k][j]*Wp[j][n] -> fused[n*512 + k] (bf16) ----
__global__ __launch_bounds__(256) void k_wtwp(const float* __restrict__ Wt,
                                              const float* __restrict__ Wp,
                                              unsigned short* __restrict__ fused) {
  __shared__ float wrow[256];
  const int k = blockIdx.x, n = threadIdx.x;
  wrow[n] = Wt[(size_t)k * 256 + n];
  __syncthreads();
  float acc = 0.f;
  for (int j = 0; j < 256; ++j) acc = fmaf(wrow[j], Wp[(size_t)j * 256 + n], acc);
  fused[(size_t)n * 512 + k] = f2bf(acc);
}

// ---- bias2[n] = bp[n] + sum_k bt[k]*Wp[k][n] ----
__global__ __launch_bounds__(256) void k_bias2(const float* __restrict__ bt,
                                               const float* __restrict__ Wp,
                                               const float* __restrict__ bp,
                                               float* __restrict__ bias2) {
  const int n = threadIdx.x;
  float acc = bp[n];
  for (int j = 0; j < 256; ++j) acc = fmaf(bt[j], Wp[(size_t)j * 256 + n], acc);
  bias2[n] = acc;
}

// ---- LayerNorm: one wave per row, 4 rows per block ----
__global__ __launch_bounds__(256) void k_ln4(const unsigned short* __restrict__ X,
                                             const float* __restrict__ g,
                                             const float* __restrict__ b,
                                             unsigned short* __restrict__ Y) {
  const int row = blockIdx.x * 4 + (threadIdx.x >> 6);
  const int lane = threadIdx.x & 63;
  const uint2 u = *(const uint2*)(X + (size_t)row * CC + lane * 4);
  const float x0 = bf2f_lo(u.x), x1 = bf2f_hi(u.x), x2 = bf2f_lo(u.y), x3 = bf2f_hi(u.y);
  float s = x0 + x1 + x2 + x3;
  float q = x0 * x0 + x1 * x1 + x2 * x2 + x3 * x3;
#pragma unroll
  for (int o = 32; o; o >>= 1) { s += __shfl_xor(s, o); q += __shfl_xor(q, o); }
  const float mean = s * (1.f / CC);
  const float var = q * (1.f / CC) - mean * mean;
  const float rs = rsqrtf(var + 1e-5f);
  const float4 g4 = *(const float4*)(g + lane * 4);
  const float4 b4 = *(const float4*)(b + lane * 4);
  uint2 o2;
  o2.x = packbf((x0 - mean) * rs * g4.x + b4.x, (x1 - mean) * rs * g4.y + b4.y);
  o2.y = packbf((x2 - mean) * rs * g4.z + b4.z, (x3 - mean) * rs * g4.w + b4.w);
  *(uint2*)(Y + (size_t)row * CC + lane * 4) = o2;
}

// ---- pipelined MFMA bf16 GEMM: BM=64, BN=256, BK=32, 512 thr, dbuf LDS ----
// AMODE 0: direct (A via global_load_lds); 2: gather*scale (reg-staged);
//       5: fused ATT A = [VPg*pk | QPg] (KD=512); 4: H window gather (KD=768)
// EPI: 0 bias; 1 gelu(acc+bias); 2 +addSrc[r]; 3 +addSrc[arow(r)];
//      4 float4 transposed f32 store out[n,col,rr]
template <int AMODE, int EPI, int KD>
__global__ __launch_bounds__(512) void k_mgemm(const unsigned short* __restrict__ A,
                                               const unsigned short* __restrict__ A2,
                                               const float* __restrict__ scaleVec,
                                               const unsigned short* __restrict__ BwT,
                                               const float* __restrict__ bias,
                                               const unsigned short* __restrict__ addSrc,
                                               unsigned short* __restrict__ Cout,
                                               float* __restrict__ FOut,
                                               int M) {
  __shared__ unsigned short As[2][64 * 32];
  __shared__ unsigned short Bs[2][256 * 32];
  const int tid = threadIdx.x;
  const int lane = tid & 63;
  const int wid = tid >> 6;
  const int wm = wid >> 2, wn = wid & 3;  // 2x4 waves, wave tile 32x64
  const int r0 = blockIdx.x * 64;
  f32x4 acc[2][4] = {};

  // A staging state: threads 0..255, one 16B chunk each
  const bool sa = tid < 256;
  const int rA = r0 + (tid >> 2);
  const int seg8 = (tid & 3) * 8;
  const bool valid = sa && (rA < M);
  int ar = 0, bb = 0, hrb = 0;
  if (valid) {
    if (AMODE == 2 || AMODE == 5) { ar = arow(rA); bb = rA / CL; }
    if (AMODE == 4) {
      const int nb = rA / 3200, rr = rA - nb * 3200;
      const int tq = rr / 25, vq = rr - tq * 25;
      hrb = (nb * CT + tq) * CL + vq;
    }
  }

  auto scale_pack = [&](uint4 t4, const float* sv) -> uint4 {
    const float4 s0 = *(const float4*)sv;
    const float4 s1 = *(const float4*)(sv + 4);
    uint4 o;
    o.x = packbf(bf2f_lo(t4.x) * s0.x, bf2f_hi(t4.x) * s0.y);
    o.y = packbf(bf2f_lo(t4.y) * s0.z, bf2f_hi(t4.y) * s0.w);
    o.z = packbf(bf2f_lo(t4.z) * s1.x, bf2f_hi(t4.z) * s1.y);
    o.w = packbf(bf2f_lo(t4.w) * s1.z, bf2f_hi(t4.w) * s1.w);
    return o;
  };
  auto loadA = [&](int k0) -> uint4 {
    uint4 u = make_uint4(0, 0, 0, 0);
    if (!valid) return u;
    if (AMODE == 2) {
      const int kg = k0 + seg8;
      u = scale_pack(*(const uint4*)(A + (size_t)ar * CC + kg), scaleVec + bb * CC + kg);
    } else if (AMODE == 5) {
      if (k0 < 256) {
        const int kg = k0 + seg8;
        u = scale_pack(*(const uint4*)(A + (size_t)ar * CC + kg), scaleVec + bb * CC + kg);
      } else {
        u = *(const uint4*)(A2 + (size_t)ar * CC + (k0 - 256) + seg8);
      }
    } else if (AMODE == 4) {
      const int w = k0 >> 8;
      u = *(const uint4*)(A + (size_t)(hrb + w * CV) * CC + (k0 & 255) + seg8);
    }
    return u;
  };
  auto stageB = [&](int buf, int k0) {
#pragma unroll
    for (int pp = 0; pp < 2; ++pp) {
      const int s = tid + pp * 512;
      gll16(BwT + (size_t)(s >> 2) * KD + k0 + (s & 3) * 8, &Bs[buf][s * 8]);
    }
  };
  auto stageAg = [&](int buf, int k0) {
    if (valid) gll16(A + (size_t)rA * CC + k0 + seg8, &As[buf][tid * 8]);
  };

  // prologue: stage K-step 0 into buffer 0
  stageB(0, 0);
  if constexpr (AMODE == 0) {
    stageAg(0, 0);
  } else {
    const uint4 a0 = loadA(0);
    if (sa) *(uint4*)(&As[0][tid * 8]) = a0;
  }
  __syncthreads();

  constexpr int NT = KD / 32;
  int cur = 0;
  for (int t = 0; t < NT; ++t) {
    const int nxt = cur ^ 1;
    const bool more = (t + 1 < NT);
    uint4 an;
    if (more) {  // issue next-tile stage BEFORE compute (latency hides under MFMA)
      stageB(nxt, (t + 1) * 32);
      if constexpr (AMODE == 0) stageAg(nxt, (t + 1) * 32);
      else an = loadA((t + 1) * 32);
    }
    bf16x8 af[2], bfr[4];
#pragma unroll
    for (int mi = 0; mi < 2; ++mi)
      af[mi] = *(const bf16x8*)(&As[cur][(wm * 32 + mi * 16 + (lane & 15)) * 32 + (lane >> 4) * 8]);
#pragma unroll
    for (int ni = 0; ni < 4; ++ni)
      bfr[ni] = *(const bf16x8*)(&Bs[cur][(wn * 64 + ni * 16 + (lane & 15)) * 32 + (lane >> 4) * 8]);
#pragma unroll
    for (int mi = 0; mi < 2; ++mi)
#pragma unroll
      for (int ni = 0; ni < 4; ++ni)
        acc[mi][ni] = __builtin_amdgcn_mfma_f32_16x16x32_bf16(af[mi], bfr[ni], acc[mi][ni], 0, 0, 0);
    if (more) {
      if constexpr (AMODE != 0) {
        if (sa) *(uint4*)(&As[nxt][tid * 8]) = an;  // vmcnt wait auto-inserted
      }
      __syncthreads();  // drains vmcnt (B gll) + lgkm (A ds_write)
      cur = nxt;
    }
  }

  const int ln15 = lane & 15, lq = lane >> 4;
#pragma unroll
  for (int mi = 0; mi < 2; ++mi) {
#pragma unroll
    for (int ni = 0; ni < 4; ++ni) {
      const int col = wn * 64 + ni * 16 + ln15;
      const float bcol = bias[col];
      if constexpr (EPI == 4) {
        const int rbase = r0 + wm * 32 + mi * 16 + lq * 4;
        const int nb = rbase / 3200, rr = rbase - nb * 3200;
        float4 v;
        v.x = acc[mi][ni][0] + bcol;
        v.y = acc[mi][ni][1] + bcol;
        v.z = acc[mi][ni][2] + bcol;
        v.w = acc[mi][ni][3] + bcol;
        *(float4*)(FOut + (size_t)nb * 819200 + (size_t)col * 3200 + rr) = v;
      } else {
#pragma unroll
        for (int rg = 0; rg < 4; ++rg) {
          const int r = r0 + wm * 32 + mi * 16 + lq * 4 + rg;
          if (r >= M) continue;
          float v = acc[mi][ni][rg] + bcol;
          if (EPI == 1) v = geluf(v);
          else if (EPI == 2) v += bf2f(addSrc[(size_t)r * CC + col]);
          else if (EPI == 3) v += bf2f(addSrc[(size_t)arow(r) * CC + col]);
          Cout[(size_t)r * CC + col] = f2bf(v);
        }
      }
    }
  }
}

// ---- rows x (256 -> 8) projection, one wave per row, 4 rows/block ----
// MODE 0: direct (QA, out [r][8]); 1: gather*pq (KWL, out [b][8][75])
template <int MODE>
__global__ __launch_bounds__(256) void k_proj8(const unsigned short* __restrict__ SRC,
                                               const float* __restrict__ pq,
                                               const float* __restrict__ Wsm,
                                               const float* __restrict__ bsm,
                                               float* __restrict__ OUT) {
  const int r = blockIdx.x * 4 + (threadIdx.x >> 6);
  const int lane = threadIdx.x & 63;
  const int c = lane * 4;
  float m0, m1, m2, m3;
  if (MODE == 0) {
    const uint2 u = *(const uint2*)(SRC + (size_t)r * CC + c);
    m0 = bf2f_lo(u.x); m1 = bf2f_hi(u.x); m2 = bf2f_lo(u.y); m3 = bf2f_hi(u.y);
  } else {
    const int ar = arow(r), bb = r / CL;
    const uint2 u = *(const uint2*)(SRC + (size_t)ar * CC + c);
    const float4 s4 = *(const float4*)(pq + bb * CC + c);
    m0 = bf2f_lo(u.x) * s4.x; m1 = bf2f_hi(u.x) * s4.y;
    m2 = bf2f_lo(u.y) * s4.z; m3 = bf2f_hi(u.y) * s4.w;
  }
  float p[8] = {};
#pragma unroll
  for (int j = 0; j < 4; ++j) {
    const float mj = (j == 0) ? m0 : (j == 1) ? m1 : (j == 2) ? m2 : m3;
#pragma unroll
    for (int h = 0; h < 8; ++h) p[h] += mj * Wsm[(c + j) * 8 + h];
  }
#pragma unroll
  for (int h = 0; h < 8; ++h) {
#pragma unroll
    for (int o = 32; o; o >>= 1) p[h] += __shfl_down(p[h], o);
  }
  if (lane == 0) {
    if (MODE == 0) {
#pragma unroll
      for (int h = 0; h < 8; ++h) OUT[(size_t)r * 8 + h] = p[h] + bsm[h];
    } else {
      const int bb = r / CL, l = r - bb * CL;
#pragma unroll
      for (int h = 0; h < 8; ++h) OUT[((size_t)bb * 8 + h) * CL + l] = p[h] + bsm[h];
    }
  }
}

// ---- softmax over l (75). MODE 0: gather from QA (26000,8); 1: in-place (B,H,L)
template <int MODE>
__global__ __launch_bounds__(128) void k_softmax(const float* __restrict__ SRC,
                                                 float* __restrict__ DST) {
  const int b = blockIdx.x;
  const int t = threadIdx.x;
  __shared__ float red[128];
  for (int h = 0; h < 8; ++h) {
    float v = -1e30f;
    if (t < CL) {
      if (MODE == 0) {
        const int ar = arow(b * CL + t);
        v = SRC[(size_t)ar * 8 + h] * SM_SCALE;
      } else {
        v = SRC[((size_t)b * 8 + h) * CL + t] * SM_SCALE;
      }
    }
    red[t] = v;
    __syncthreads();
    for (int s2 = 64; s2; s2 >>= 1) {
      if (t < s2) red[t] = fmaxf(red[t], red[t + s2]);
      __syncthreads();
    }
    const float mx = red[0];
    __syncthreads();
    const float e = (t < CL) ? __expf(v - mx) : 0.f;
    red[t] = e;
    __syncthreads();
    for (int s2 = 64; s2; s2 >>= 1) {
      if (t < s2) red[t] += red[t + s2];
      __syncthreads();
    }
    const float inv = 1.f / red[0];
    __syncthreads();
    if (t < CL) DST[((size_t)b * 8 + h) * CL + t] = e * inv;
    __syncthreads();
  }
}

// ---- pooled vector: OUT[b,c] = sum_l WGT[b, c>>5, l] * SRC[arow(b,l), c] ----
__global__ __launch_bounds__(256) void k_pool(const float* __restrict__ WGT,
                                              const unsigned short* __restrict__ SRC,
                                              float* __restrict__ OUT) {
  const int b = blockIdx.x;
  const int c = threadIdx.x;
  __shared__ int ar[CL];
  __shared__ float wg[8 * CL];
  if (c < CL) ar[c] = arow(b * CL + c);
  for (int i = c; i < 8 * CL; i += 256) wg[i] = WGT[(size_t)b * 8 * CL + i];
  __syncthreads();
  const int h = c >> 5;
  float acc = 0.f;
  for (int l = 0; l < CL; ++l) acc += wg[h * CL + l] * bf2f(SRC[(size_t)ar[l] * CC + c]);
  OUT[(size_t)b * CC + c] = acc;
}

extern "C" void kernel_launch(void* const* d_in, const int* in_sizes, int n_in,
                              void* d_out, int out_size, void* d_ws, size_t ws_size,
                              hipStream_t stream) {
  const float* x = (const float*)d_in[0];
  const float* ln1_g = (const float*)d_in[1];
  const float* ln1_b = (const float*)d_in[2];
  const float* Wq = (const float*)d_in[3];
  const float* bq = (const float*)d_in[4];
  const float* Wqa = (const float*)d_in[5];
  const float* bqa = (const float*)d_in[6];
  const float* Wk = (const float*)d_in[7];
  const float* bk = (const float*)d_in[8];
  const float* Wka = (const float*)d_in[9];
  const float* bka = (const float*)d_in[10];
  const float* Wv = (const float*)d_in[11];
  const float* bv = (const float*)d_in[12];
  const float* Wt = (const float*)d_in[13];
  const float* bt = (const float*)d_in[14];
  const float* Wp = (const float*)d_in[15];
  const float* bp = (const float*)d_in[16];
  const float* ffn_g = (const float*)d_in[17];
  const float* ffn_b = (const float*)d_in[18];
  const float* W1 = (const float*)d_in[19];
  const float* b1 = (const float*)d_in[20];
  const float* W2 = (const float*)d_in[21];
  const float* b2 = (const float*)d_in[22];
  const float* tn_g = (const float*)d_in[23];
  const float* tn_b = (const float*)d_in[24];
  const float* c1w = (const float*)d_in[25];
  const float* c1b = (const float*)d_in[26];
  const float* c2w = (const float*)d_in[27];
  const float* c2b = (const float*)d_in[28];
  float* out = (float*)d_out;

  char* wp = (char*)d_ws;
  auto alloc = [&](size_t bytes) -> char* {
    char* p = wp;
    wp += (bytes + 255) & ~(size_t)255;
    return p;
  };
  unsigned short* XTP = (unsigned short*)alloc((size_t)MPAD * CC * 2);
  unsigned short* LNXP = (unsigned short*)alloc((size_t)MPAD * CC * 2);
  unsigned short* QP = (unsigned short*)alloc((size_t)MPAD * CC * 2);
  unsigned short* KP = (unsigned short*)alloc((size_t)MPAD * CC * 2);
  unsigned short* VP = (unsigned short*)alloc((size_t)MPAD * CC * 2);
  unsigned short* KVb = (unsigned short*)alloc((size_t)MBL * CC * 2);   // F / TN
  unsigned short* ATTb = (unsigned short*)alloc((size_t)MBL * CC * 2);  // ATT -> H
  unsigned short* Gb = (unsigned short*)alloc((size_t)MBL * CC * 2);
  unsigned short* Yb = (unsigned short*)alloc((size_t)MBL * CC * 2);
  float* QA = (float*)alloc((size_t)MPAD * 8 * 4);
  float* QW = (float*)alloc((size_t)1024 * 8 * CL * 4);
  float* KWL = (float*)alloc((size_t)1024 * 8 * CL * 4);
  float* PQ = (float*)alloc((size_t)1024 * CC * 4);
  float* PK = (float*)alloc((size_t)1024 * CC * 4);
  unsigned short* WqT = (unsigned short*)alloc(256 * 256 * 2);
  unsigned short* WkT = (unsigned short*)alloc(256 * 256 * 2);
  unsigned short* WvT = (unsigned short*)alloc(256 * 256 * 2);
  unsigned short* W1T = (unsigned short*)alloc(256 * 256 * 2);
  unsigned short* W2T = (unsigned short*)alloc(256 * 256 * 2);
  unsigned short* c1wT = (unsigned short*)alloc(256 * 256 * 2);
  unsigned short* c2wT = (unsigned short*)alloc(256 * 768 * 2);
  unsigned short* fusedB = (unsigned short*)alloc(256 * 512 * 2);  // [WtWp | Wp]^T
  float* bias2 = (float*)alloc(256 * 4);

  // weight prep: dst[n*stride+off+k] = bf16(src[k][n])
  TJobs J;
  const float* srcs[10] = {Wq, Wk, Wv, W1, W2, c1w, c2w, c2w + 65536, c2w + 131072, Wp};
  unsigned short* dsts[10] = {WqT, WkT, WvT, W1T, W2T, c1wT, c2wT, c2wT, c2wT, fusedB};
  const int strides[10] = {256, 256, 256, 256, 256, 256, 768, 768, 768, 512};
  const int offs[10] = {0, 0, 0, 0, 0, 0, 0, 256, 512, 256};
  for (int i = 0; i < 10; ++i) {
    J.src[i] = srcs[i]; J.dst[i] = dsts[i]; J.stride[i] = strides[i]; J.off[i] = offs[i];
  }
  k_wtrans<<<dim3(8, 8, 10), 256, 0, stream>>>(J);
  k_wtwp<<<256, 256, 0, stream>>>(Wt, Wp, fusedB);
  k_bias2<<<1, 256, 0, stream>>>(bt, Wp, bp, bias2);

  k_transpose<<<dim3(8, 100, 8), 256, 0, stream>>>(x, XTP);
  k_zero_pad<<<400, 256, 0, stream>>>(XTP);
  k_ln4<<<MPAD / 4, 256, 0, stream>>>(XTP, ln1_g, ln1_b, LNXP);

  const int gP = (MPAD + 63) / 64;  // 407
  const int gB = MBL / 64;          // 1200
  const int gO = MOUT / 64;         // 400
  k_mgemm<0, 0, 256><<<gP, 512, 0, stream>>>(LNXP, nullptr, nullptr, WqT, bq, nullptr, QP, nullptr, MPAD);
  k_mgemm<0, 0, 256><<<gP, 512, 0, stream>>>(LNXP, nullptr, nullptr, WkT, bk, nullptr, KP, nullptr, MPAD);
  k_mgemm<0, 0, 256><<<gP, 512, 0, stream>>>(LNXP, nullptr, nullptr, WvT, bv, nullptr, VP, nullptr, MPAD);

  k_proj8<0><<<MPAD / 4, 256, 0, stream>>>(QP, nullptr, Wqa, bqa, QA);
  k_softmax<0><<<1024, 128, 0, stream>>>(QA, QW);
  k_pool<<<1024, 256, 0, stream>>>(QW, QP, PQ);

  k_proj8<1><<<MBL / 4, 256, 0, stream>>>(KP, PQ, Wka, bka, KWL);
  k_softmax<1><<<1024, 128, 0, stream>>>(KWL, KWL);
  k_pool<<<1024, 256, 0, stream>>>(KWL, KP, PK);

  // ATT = [VPg*pk | QPg] @ [[WtWp];[Wp]] + bias2 + XTPg
  k_mgemm<5, 3, 512><<<gB, 512, 0, stream>>>(VP, QP, PK, fusedB, bias2, XTP, ATTb, nullptr, MBL);

  k_ln4<<<MBL / 4, 256, 0, stream>>>(ATTb, ffn_g, ffn_b, KVb);  // F
  k_mgemm<0, 1, 256><<<gB, 512, 0, stream>>>(KVb, nullptr, nullptr, W1T, b1, nullptr, Gb, nullptr, MBL);
  k_mgemm<0, 2, 256><<<gB, 512, 0, stream>>>(Gb, nullptr, nullptr, W2T, b2, ATTb, Yb, nullptr, MBL);

  k_ln4<<<MBL / 4, 256, 0, stream>>>(Yb, tn_g, tn_b, KVb);  // TN
  k_mgemm<0, 1, 256><<<gB, 512, 0, stream>>>(KVb, nullptr, nullptr, c1wT, c1b, nullptr, ATTb, nullptr, MBL);  // H

  k_mgemm<4, 4, 768><<<gO, 512, 0, stream>>>(ATTb, nullptr, nullptr, c2wT, c2b, nullptr, nullptr, out, MOUT);
}

// Round 8
// 408.871 us; speedup vs baseline: 3.8409x; 1.0931x over previous
//
#include <hip/hip_runtime.h>

// ---------------------------------------------------------------------------
// Pipeline (intermediates bf16, f32 accum; all big GEMMs on pipelined MFMA):
//   x (N,C,T,V) f32 --transpose--> XTP (N,T+2,V,C) bf16 (boundary frames = 0)
//   LNXP = LN(XTP, ln1)                  [26000 rows; 3x dedup vs (B,L)]
//   QP/KP/VP = LNXP @ W{q,k,v} + b       [MFMA, global_load_lds both operands]
//   QA = QP @ Wqa + bqa                  [26000 x 8, dedup'd]
//   PQ = attpool<0>(QP rows, QA)         [fused softmax+pool, 1 block/b]
//   PK = attpool<1>(KP rows, PQ, Wka)    [fused logits+softmax+pool]
//   ATT = [VPg*pk | QPg] @ [[Wt*Wp];[Wp]] + (bt*Wp+bp) + XTPg   [MFMA K=512]
//   F = LN(ATT); G = gelu(F@W1+b1); Y = G@W2+b2+ATT  [MFMA]
//   TN = LN(Y);  H = gelu(TN@c1w+c1b)                [MFMA]
//   out = H-window-contraction @ c2w + c2b           [MFMA K=768, float4
//                                                     transposed store]
// ---------------------------------------------------------------------------

#define DI __device__ __forceinline__

constexpr int CC   = 256;
constexpr int CL   = 75;
constexpr int CV   = 25;
constexpr int CT   = 128;
constexpr int TP   = 130;          // T+2 padded frames
constexpr int MPAD = 8 * TP * CV;  // 26000
constexpr int MBL  = 1024 * CL;    // 76800
constexpr int MOUT = 8 * CT * CV;  // 25600
constexpr float SM_SCALE = 0.17677669529663687f;  // 1/sqrt(32)

typedef __bf16 bf16x8 __attribute__((ext_vector_type(8)));
typedef float f32x4 __attribute__((ext_vector_type(4)));

DI float bf2f(unsigned short u) { return __uint_as_float(((unsigned)u) << 16); }
DI float bf2f_lo(unsigned u) { return __uint_as_float(u << 16); }
DI float bf2f_hi(unsigned u) { return __uint_as_float(u & 0xffff0000u); }
DI unsigned short f2bf(float f) {
  unsigned u = __float_as_uint(f);
  u += 0x7fffu + ((u >> 16) & 1u);
  return (unsigned short)(u >> 16);
}
DI unsigned packbf(float a, float b) {
  return (unsigned)f2bf(a) | ((unsigned)f2bf(b) << 16);
}
DI float geluf(float x) { return 0.5f * x * (1.f + erff(x * 0.70710678118654752440f)); }

// async global->LDS, 16B per lane (dest = wave-uniform base + lane*16)
DI void gll16(const unsigned short* g, unsigned short* l) {
  __builtin_amdgcn_global_load_lds(
      (const __attribute__((address_space(1))) unsigned int*)g,
      (__attribute__((address_space(3))) unsigned int*)l, 16, 0, 0);
}

// (B,L) row -> padded-frame row: r=(b,l), b=n*128+t, l=w*25+v -> (n*130+t+w)*25+v
DI int arow(int r) {
  int b = r / CL;
  int l = r - b * CL;
  int w = l / CV;
  int v = l - w * CV;
  int t = b & (CT - 1);
  int n = b >> 7;
  return (n * TP + t + w) * CV + v;
}

// ---- x (N,C,T,V) f32 -> XTP (N,T+2,V,C) bf16, interior frames ----
__global__ __launch_bounds__(256) void k_transpose(const float* __restrict__ x,
                                                   unsigned short* __restrict__ xtp) {
  __shared__ float tile[32][33];
  const int n = blockIdx.z;
  const int c0 = blockIdx.x * 32;
  const int tv0 = blockIdx.y * 32;
  const int tx = threadIdx.x & 31, ty = threadIdx.x >> 5;
#pragma unroll
  for (int j = 0; j < 32; j += 8) {
    tile[ty + j][tx] = x[((size_t)(n * CC + c0 + ty + j)) * 3200 + tv0 + tx];
  }
  __syncthreads();
#pragma unroll
  for (int j = 0; j < 32; j += 8) {
    int tv = tv0 + ty + j;
    int st = tv / CV, v = tv - st * CV;
    size_t row = ((size_t)n * TP + st + 1) * CV + v;
    xtp[row * CC + c0 + tx] = f2bf(tile[tx][ty + j]);
  }
}

// ---- zero the boundary frames (st = -1 and st = T) ----
__global__ __launch_bounds__(256) void k_zero_pad(unsigned short* __restrict__ xtp) {
  int i = blockIdx.x * 256 + threadIdx.x;  // 400*256 = 102400 exact
  int c = i & 255;
  int rid = i >> 8;
  int n = rid / 50;
  int rem = rid - n * 50;
  int side = rem / 25;
  int v = rem - side * 25;
  size_t row = ((size_t)n * TP + side * (TP - 1)) * CV + v;
  xtp[row * CC + c] = 0;
}

// ---- weight transpose+convert: dst[n*stride + off + k] = f2bf(src[k*256+n]) ----
struct TJobs {
  const float* src[10];
  unsigned short* dst[10];
  int stride[10];
  int off[10];
};
__global__ __launch_bounds__(256) void k_wtrans(TJobs J) {
  __shared__ float tile[32][33];
  const int j = blockIdx.z;
  const float* src = J.src[j];
  unsigned short* dst = J.dst[j];
  const int stride = J.stride[j], off = J.off[j];
  const int k0 = blockIdx.x * 32, n0 = blockIdx.y * 32;
  const int tx = threadIdx.x & 31, ty = threadIdx.x >> 5;
#pragma unroll
  for (int jj = 0; jj < 32; jj += 8)
    tile[ty + jj][tx] = src[(size_t)(k0 + ty + jj) * 256 + n0 + tx];
  __syncthreads();
#pragma unroll
  for (int jj = 0; jj < 32; jj += 8)
    dst[(size_t)(n0 + ty + jj) * stride + off + k0 + tx] = f2bf(tile[tx][ty + jj]);
}

// ---- WtWp[k][n] = sum_j Wt[k][j]*Wp[j][n] -> fused[n*512 + k] (bf16) ----
__global__ __launch_bounds__(256) void k_wtwp(const float* __restrict__ Wt,
                                              const float* __restrict__ Wp,
                                              unsigned short* __restrict__ fused) {
  __shared__ float wrow[256];
  const int k = blockIdx.x, n = threadIdx.x;
  wrow[n] = Wt[(size_t)k * 256 + n];
  __syncthreads();
  float acc = 0.f;
  for (int j = 0; j < 256; ++j) acc = fmaf(wrow[j], Wp[(size_t)j * 256 + n], acc);
  fused[(size_t)n * 512 + k] = f2bf(acc);
}

// ---- bias2[n] = bp[n] + sum_k bt[k]*Wp[k][n] ----
__global__ __launch_bounds__(256) void k_bias2(const float* __restrict__ bt,
                                               const float* __restrict__ Wp,
                                               const float* __restrict__ bp,
                                               float* __restrict__ bias2) {
  const int n = threadIdx.x;
  float acc = bp[n];
  for (int j = 0; j < 256; ++j) acc = fmaf(bt[j], Wp[(size_t)j * 256 + n], acc);
  bias2[n] = acc;
}

// ---- LayerNorm: one wave per row, 4 rows per block ----
__global__ __launch_bounds__(256) void k_ln4(const unsigned short* __restrict__ X,
                                             const float* __restrict__ g,
                                             const float* __restrict__ b,
                                             unsigned short* __restrict__ Y) {
  const int row = blockIdx.x * 4 + (threadIdx.x >> 6);
  const int lane = threadIdx.x & 63;
  const uint2 u = *(const uint2*)(X + (size_t)row * CC + lane * 4);
  const float x0 = bf2f_lo(u.x), x1 = bf2f_hi(u.x), x2 = bf2f_lo(u.y), x3 = bf2f_hi(u.y);
  float s = x0 + x1 + x2 + x3;
  float q = x0 * x0 + x1 * x1 + x2 * x2 + x3 * x3;
#pragma unroll
  for (int o = 32; o; o >>= 1) { s += __shfl_xor(s, o); q += __shfl_xor(q, o); }
  const float mean = s * (1.f / CC);
  const float var = q * (1.f / CC) - mean * mean;
  const float rs = rsqrtf(var + 1e-5f);
  const float4 g4 = *(const float4*)(g + lane * 4);
  const float4 b4 = *(const float4*)(b + lane * 4);
  uint2 o2;
  o2.x = packbf((x0 - mean) * rs * g4.x + b4.x, (x1 - mean) * rs * g4.y + b4.y);
  o2.y = packbf((x2 - mean) * rs * g4.z + b4.z, (x3 - mean) * rs * g4.w + b4.w);
  *(uint2*)(Y + (size_t)row * CC + lane * 4) = o2;
}

// ---- pipelined MFMA bf16 GEMM: BM=64, BN=256, BK=32, 512 thr, dbuf LDS ----
// AMODE 0: direct (A via global_load_lds);
//       5: fused ATT A = [VPg*pk | QPg] (KD=512); 4: H window gather (KD=768)
// EPI: 0 bias; 1 gelu(acc+bias); 2 +addSrc[r]; 3 +addSrc[arow(r)];
//      4 float4 transposed f32 store out[n,col,rr]
template <int AMODE, int EPI, int KD>
__global__ __launch_bounds__(512) void k_mgemm(const unsigned short* __restrict__ A,
                                               const unsigned short* __restrict__ A2,
                                               const float* __restrict__ scaleVec,
                                               const unsigned short* __restrict__ BwT,
                                               const float* __restrict__ bias,
                                               const unsigned short* __restrict__ addSrc,
                                               unsigned short* __restrict__ Cout,
                                               float* __restrict__ FOut,
                                               int M) {
  __shared__ unsigned short As[2][64 * 32];
  __shared__ unsigned short Bs[2][256 * 32];
  const int tid = threadIdx.x;
  const int lane = tid & 63;
  const int wid = tid >> 6;
  const int wm = wid >> 2, wn = wid & 3;  // 2x4 waves, wave tile 32x64
  const int r0 = blockIdx.x * 64;
  f32x4 acc[2][4] = {};

  // A staging state: threads 0..255, one 16B chunk each
  const bool sa = tid < 256;
  const int rA = r0 + (tid >> 2);
  const int seg8 = (tid & 3) * 8;
  const bool valid = sa && (rA < M);
  int ar = 0, bb = 0, hrb = 0;
  if (valid) {
    if (AMODE == 5) { ar = arow(rA); bb = rA / CL; }
    if (AMODE == 4) {
      const int nb = rA / 3200, rr = rA - nb * 3200;
      const int tq = rr / 25, vq = rr - tq * 25;
      hrb = (nb * CT + tq) * CL + vq;
    }
  }

  auto scale_pack = [&](uint4 t4, const float* sv) -> uint4 {
    const float4 s0 = *(const float4*)sv;
    const float4 s1 = *(const float4*)(sv + 4);
    uint4 o;
    o.x = packbf(bf2f_lo(t4.x) * s0.x, bf2f_hi(t4.x) * s0.y);
    o.y = packbf(bf2f_lo(t4.y) * s0.z, bf2f_hi(t4.y) * s0.w);
    o.z = packbf(bf2f_lo(t4.z) * s1.x, bf2f_hi(t4.z) * s1.y);
    o.w = packbf(bf2f_lo(t4.w) * s1.z, bf2f_hi(t4.w) * s1.w);
    return o;
  };
  auto loadA = [&](int k0) -> uint4 {
    uint4 u = make_uint4(0, 0, 0, 0);
    if (!valid) return u;
    if (AMODE == 5) {
      if (k0 < 256) {
        const int kg = k0 + seg8;
        u = scale_pack(*(const uint4*)(A + (size_t)ar * CC + kg), scaleVec + bb * CC + kg);
      } else {
        u = *(const uint4*)(A2 + (size_t)ar * CC + (k0 - 256) + seg8);
      }
    } else if (AMODE == 4) {
      const int w = k0 >> 8;
      u = *(const uint4*)(A + (size_t)(hrb + w * CV) * CC + (k0 & 255) + seg8);
    }
    return u;
  };
  auto stageB = [&](int buf, int k0) {
#pragma unroll
    for (int pp = 0; pp < 2; ++pp) {
      const int s = tid + pp * 512;
      gll16(BwT + (size_t)(s >> 2) * KD + k0 + (s & 3) * 8, &Bs[buf][s * 8]);
    }
  };
  auto stageAg = [&](int buf, int k0) {
    if (valid) gll16(A + (size_t)rA * CC + k0 + seg8, &As[buf][tid * 8]);
  };

  // prologue: stage K-step 0 into buffer 0
  stageB(0, 0);
  if constexpr (AMODE == 0) {
    stageAg(0, 0);
  } else {
    const uint4 a0 = loadA(0);
    if (sa) *(uint4*)(&As[0][tid * 8]) = a0;
  }
  __syncthreads();

  constexpr int NT = KD / 32;
  int cur = 0;
  for (int t = 0; t < NT; ++t) {
    const int nxt = cur ^ 1;
    const bool more = (t + 1 < NT);
    uint4 an;
    if (more) {  // issue next-tile stage BEFORE compute (latency hides under MFMA)
      stageB(nxt, (t + 1) * 32);
      if constexpr (AMODE == 0) stageAg(nxt, (t + 1) * 32);
      else an = loadA((t + 1) * 32);
    }
    bf16x8 af[2], bfr[4];
#pragma unroll
    for (int mi = 0; mi < 2; ++mi)
      af[mi] = *(const bf16x8*)(&As[cur][(wm * 32 + mi * 16 + (lane & 15)) * 32 + (lane >> 4) * 8]);
#pragma unroll
    for (int ni = 0; ni < 4; ++ni)
      bfr[ni] = *(const bf16x8*)(&Bs[cur][(wn * 64 + ni * 16 + (lane & 15)) * 32 + (lane >> 4) * 8]);
#pragma unroll
    for (int mi = 0; mi < 2; ++mi)
#pragma unroll
      for (int ni = 0; ni < 4; ++ni)
        acc[mi][ni] = __builtin_amdgcn_mfma_f32_16x16x32_bf16(af[mi], bfr[ni], acc[mi][ni], 0, 0, 0);
    if (more) {
      if constexpr (AMODE != 0) {
        if (sa) *(uint4*)(&As[nxt][tid * 8]) = an;  // vmcnt wait auto-inserted
      }
      __syncthreads();  // drains vmcnt (B gll) + lgkm (A ds_write)
      cur = nxt;
    }
  }

  const int ln15 = lane & 15, lq = lane >> 4;
#pragma unroll
  for (int mi = 0; mi < 2; ++mi) {
#pragma unroll
    for (int ni = 0; ni < 4; ++ni) {
      const int col = wn * 64 + ni * 16 + ln15;
      const float bcol = bias[col];
      if constexpr (EPI == 4) {
        const int rbase = r0 + wm * 32 + mi * 16 + lq * 4;
        const int nb = rbase / 3200, rr = rbase - nb * 3200;
        float4 v;
        v.x = acc[mi][ni][0] + bcol;
        v.y = acc[mi][ni][1] + bcol;
        v.z = acc[mi][ni][2] + bcol;
        v.w = acc[mi][ni][3] + bcol;
        *(float4*)(FOut + (size_t)nb * 819200 + (size_t)col * 3200 + rr) = v;
      } else {
#pragma unroll
        for (int rg = 0; rg < 4; ++rg) {
          const int r = r0 + wm * 32 + mi * 16 + lq * 4 + rg;
          if (r >= M) continue;
          float v = acc[mi][ni][rg] + bcol;
          if (EPI == 1) v = geluf(v);
          else if (EPI == 2) v += bf2f(addSrc[(size_t)r * CC + col]);
          else if (EPI == 3) v += bf2f(addSrc[(size_t)arow(r) * CC + col]);
          Cout[(size_t)r * CC + col] = f2bf(v);
        }
      }
    }
  }
}

// ---- rows x (256 -> 8) projection (QA), one wave per row, 4 rows/block ----
__global__ __launch_bounds__(256) void k_proj8(const unsigned short* __restrict__ SRC,
                                               const float* __restrict__ Wsm,
                                               const float* __restrict__ bsm,
                                               float* __restrict__ OUT) {
  const int r = blockIdx.x * 4 + (threadIdx.x >> 6);
  const int lane = threadIdx.x & 63;
  const int c = lane * 4;
  const uint2 u = *(const uint2*)(SRC + (size_t)r * CC + c);
  const float m0 = bf2f_lo(u.x), m1 = bf2f_hi(u.x), m2 = bf2f_lo(u.y), m3 = bf2f_hi(u.y);
  float p[8] = {};
#pragma unroll
  for (int j = 0; j < 4; ++j) {
    const float mj = (j == 0) ? m0 : (j == 1) ? m1 : (j == 2) ? m2 : m3;
#pragma unroll
    for (int h = 0; h < 8; ++h) p[h] += mj * Wsm[(c + j) * 8 + h];
  }
#pragma unroll
  for (int h = 0; h < 8; ++h) {
#pragma unroll
    for (int o = 32; o; o >>= 1) p[h] += __shfl_down(p[h], o);
  }
  if (lane == 0) {
#pragma unroll
    for (int h = 0; h < 8; ++h) OUT[(size_t)r * 8 + h] = p[h] + bsm[h];
  }
}

// ---- fused attention pool: one block per b (1024 blocks, 256 threads) ----
// SIDE 0 (Q): logits gathered from QA[26000][8]; OUT[b][c] = sum_l sm(qa)[h(c)][l]*ROWS[ar(l)][c]
// SIDE 1 (K): logits = (ROWS[ar(l)] .* PQ[b]) @ Wka + bka, scaled; pool same with KP.
template <int SIDE>
__global__ __launch_bounds__(256) void k_attpool(const unsigned short* __restrict__ ROWS,
                                                 const float* __restrict__ QA,
                                                 const float* __restrict__ PQ,
                                                 const float* __restrict__ Wka,
                                                 const float* __restrict__ bka,
                                                 float* __restrict__ OUT) {
  __shared__ unsigned short rows[CL * CC];  // 38400 B
  __shared__ float uu[CC * 8];              // SIDE1: pq*Wka (8 KB)
  __shared__ float lg[8 * 76];              // logits/weights per (h,l)
  __shared__ float inv8[8];
  __shared__ int arl[CL];
  const int b = blockIdx.x;
  const int t = threadIdx.x;

  if (t < CL) arl[t] = arow(b * CL + t);
  __syncthreads();

  // stage the 75 gathered rows (each 512 B) coalesced, 16 B per thread-item
  for (int i = t; i < CL * 32; i += 256) {
    const int r = i >> 5, seg = i & 31;
    *(uint4*)&rows[r * CC + seg * 8] = *(const uint4*)(ROWS + (size_t)arl[r] * CC + seg * 8);
  }
  if constexpr (SIDE == 0) {
    // logits straight from QA gather: 75 rows x 8 f32 (two float4 per row)
    for (int i = t; i < CL * 2; i += 256) {
      const int l = i >> 1, q = i & 1;
      const float4 v = *(const float4*)(QA + (size_t)arl[l] * 8 + q * 4);
      lg[(q * 4 + 0) * 76 + l] = v.x * SM_SCALE;
      lg[(q * 4 + 1) * 76 + l] = v.y * SM_SCALE;
      lg[(q * 4 + 2) * 76 + l] = v.z * SM_SCALE;
      lg[(q * 4 + 3) * 76 + l] = v.w * SM_SCALE;
    }
  } else {
    for (int i = t; i < CC * 8; i += 256) {
      const int c = i >> 3, h = i & 7;
      uu[i] = PQ[(size_t)b * CC + c] * Wka[c * 8 + h];
    }
  }
  __syncthreads();

  if constexpr (SIDE == 1) {
    // 600 dot-256 products from LDS
    for (int i = t; i < CL * 8; i += 256) {
      const int h = i / CL, l = i - h * CL;
      float acc = bka[h];
#pragma unroll 4
      for (int c = 0; c < CC; c += 2) {
        const unsigned pr = *(const unsigned*)&rows[l * CC + c];
        acc = fmaf(bf2f_lo(pr), uu[c * 8 + h], acc);
        acc = fmaf(bf2f_hi(pr), uu[c * 8 + h + 8], acc);
      }
      lg[h * 76 + l] = acc * SM_SCALE;
    }
    __syncthreads();
  }

  // softmax over l per h (8 threads, 75 serial — negligible vs dot phase)
  if (t < 8) {
    float m = -1e30f;
    for (int l = 0; l < CL; ++l) m = fmaxf(m, lg[t * 76 + l]);
    float s = 0.f;
    for (int l = 0; l < CL; ++l) {
      const float e = __expf(lg[t * 76 + l] - m);
      lg[t * 76 + l] = e;
      s += e;
    }
    inv8[t] = 1.f / s;
  }
  __syncthreads();

  // pool: thread c: OUT[b][c] = inv * sum_l e[h(c)][l] * rows[l][c]
  {
    const int h = t >> 5;
    float acc = 0.f;
    for (int l = 0; l < CL; ++l) acc = fmaf(lg[h * 76 + l], bf2f(rows[l * CC + t]), acc);
    OUT[(size_t)b * CC + t] = acc * inv8[h];
  }
}

extern "C" void kernel_launch(void* const* d_in, const int* in_sizes, int n_in,
                              void* d_out, int out_size, void* d_ws, size_t ws_size,
                              hipStream_t stream) {
  const float* x = (const float*)d_in[0];
  const float* ln1_g = (const float*)d_in[1];
  const float* ln1_b = (const float*)d_in[2];
  const float* Wq = (const float*)d_in[3];
  const float* bq = (const float*)d_in[4];
  const float* Wqa = (const float*)d_in[5];
  const float* bqa = (const float*)d_in[6];
  const float* Wk = (const float*)d_in[7];
  const float* bk = (const float*)d_in[8];
  const float* Wka = (const float*)d_in[9];
  const float* bka = (const float*)d_in[10];
  const float* Wv = (const float*)d_in[11];
  const float* bv = (const float*)d_in[12];
  const float* Wt = (const float*)d_in[13];
  const float* bt = (const float*)d_in[14];
  const float* Wp = (const float*)d_in[15];
  const float* bp = (const float*)d_in[16];
  const float* ffn_g = (const float*)d_in[17];
  const float* ffn_b = (const float*)d_in[18];
  const float* W1 = (const float*)d_in[19];
  const float* b1 = (const float*)d_in[20];
  const float* W2 = (const float*)d_in[21];
  const float* b2 = (const float*)d_in[22];
  const float* tn_g = (const float*)d_in[23];
  const float* tn_b = (const float*)d_in[24];
  const float* c1w = (const float*)d_in[25];
  const float* c1b = (const float*)d_in[26];
  const float* c2w = (const float*)d_in[27];
  const float* c2b = (const float*)d_in[28];
  float* out = (float*)d_out;

  char* wp = (char*)d_ws;
  auto alloc = [&](size_t bytes) -> char* {
    char* p = wp;
    wp += (bytes + 255) & ~(size_t)255;
    return p;
  };
  unsigned short* XTP = (unsigned short*)alloc((size_t)MPAD * CC * 2);
  unsigned short* LNXP = (unsigned short*)alloc((size_t)MPAD * CC * 2);
  unsigned short* QP = (unsigned short*)alloc((size_t)MPAD * CC * 2);
  unsigned short* KP = (unsigned short*)alloc((size_t)MPAD * CC * 2);
  unsigned short* VP = (unsigned short*)alloc((size_t)MPAD * CC * 2);
  unsigned short* KVb = (unsigned short*)alloc((size_t)MBL * CC * 2);   // F / TN
  unsigned short* ATTb = (unsigned short*)alloc((size_t)MBL * CC * 2);  // ATT -> H
  unsigned short* Gb = (unsigned short*)alloc((size_t)MBL * CC * 2);
  unsigned short* Yb = (unsigned short*)alloc((size_t)MBL * CC * 2);
  float* QA = (float*)alloc((size_t)MPAD * 8 * 4);
  float* PQ = (float*)alloc((size_t)1024 * CC * 4);
  float* PK = (float*)alloc((size_t)1024 * CC * 4);
  unsigned short* WqT = (unsigned short*)alloc(256 * 256 * 2);
  unsigned short* WkT = (unsigned short*)alloc(256 * 256 * 2);
  unsigned short* WvT = (unsigned short*)alloc(256 * 256 * 2);
  unsigned short* W1T = (unsigned short*)alloc(256 * 256 * 2);
  unsigned short* W2T = (unsigned short*)alloc(256 * 256 * 2);
  unsigned short* c1wT = (unsigned short*)alloc(256 * 256 * 2);
  unsigned short* c2wT = (unsigned short*)alloc(256 * 768 * 2);
  unsigned short* fusedB = (unsigned short*)alloc(256 * 512 * 2);  // [WtWp | Wp]^T
  float* bias2 = (float*)alloc(256 * 4);

  // weight prep: dst[n*stride+off+k] = bf16(src[k][n])
  TJobs J;
  const float* srcs[10] = {Wq, Wk, Wv, W1, W2, c1w, c2w, c2w + 65536, c2w + 131072, Wp};
  unsigned short* dsts[10] = {WqT, WkT, WvT, W1T, W2T, c1wT, c2wT, c2wT, c2wT, fusedB};
  const int strides[10] = {256, 256, 256, 256, 256, 256, 768, 768, 768, 512};
  const int offs[10] = {0, 0, 0, 0, 0, 0, 0, 256, 512, 256};
  for (int i = 0; i < 10; ++i) {
    J.src[i] = srcs[i]; J.dst[i] = dsts[i]; J.stride[i] = strides[i]; J.off[i] = offs[i];
  }
  k_wtrans<<<dim3(8, 8, 10), 256, 0, stream>>>(J);
  k_wtwp<<<256, 256, 0, stream>>>(Wt, Wp, fusedB);
  k_bias2<<<1, 256, 0, stream>>>(bt, Wp, bp, bias2);

  k_transpose<<<dim3(8, 100, 8), 256, 0, stream>>>(x, XTP);
  k_zero_pad<<<400, 256, 0, stream>>>(XTP);
  k_ln4<<<MPAD / 4, 256, 0, stream>>>(XTP, ln1_g, ln1_b, LNXP);

  const int gP = (MPAD + 63) / 64;  // 407
  const int gB = MBL / 64;          // 1200
  const int gO = MOUT / 64;         // 400
  k_mgemm<0, 0, 256><<<gP, 512, 0, stream>>>(LNXP, nullptr, nullptr, WqT, bq, nullptr, QP, nullptr, MPAD);
  k_mgemm<0, 0, 256><<<gP, 512, 0, stream>>>(LNXP, nullptr, nullptr, WkT, bk, nullptr, KP, nullptr, MPAD);
  k_mgemm<0, 0, 256><<<gP, 512, 0, stream>>>(LNXP, nullptr, nullptr, WvT, bv, nullptr, VP, nullptr, MPAD);

  k_proj8<<<MPAD / 4, 256, 0, stream>>>(QP, Wqa, bqa, QA);
  k_attpool<0><<<1024, 256, 0, stream>>>(QP, QA, nullptr, nullptr, nullptr, PQ);
  k_attpool<1><<<1024, 256, 0, stream>>>(KP, nullptr, PQ, Wka, bka, PK);

  // ATT = [VPg*pk | QPg] @ [[WtWp];[Wp]] + bias2 + XTPg
  k_mgemm<5, 3, 512><<<gB, 512, 0, stream>>>(VP, QP, PK, fusedB, bias2, XTP, ATTb, nullptr, MBL);

  k_ln4<<<MBL / 4, 256, 0, stream>>>(ATTb, ffn_g, ffn_b, KVb);  // F
  k_mgemm<0, 1, 256><<<gB, 512, 0, stream>>>(KVb, nullptr, nullptr, W1T, b1, nullptr, Gb, nullptr, MBL);
  k_mgemm<0, 2, 256><<<gB, 512, 0, stream>>>(Gb, nullptr, nullptr, W2T, b2, ATTb, Yb, nullptr, MBL);

  k_ln4<<<MBL / 4, 256, 0, stream>>>(Yb, tn_g, tn_b, KVb);  // TN
  k_mgemm<0, 1, 256><<<gB, 512, 0, stream>>>(KVb, nullptr, nullptr, c1wT, c1b, nullptr, ATTb, nullptr, MBL);  // H

  k_mgemm<4, 4, 768><<<gO, 512, 0, stream>>>(ATTb, nullptr, nullptr, c2wT, c2b, nullptr, nullptr, out, MOUT);
}

// Round 9
// 383.726 us; speedup vs baseline: 4.0925x; 1.0655x over previous
//
#include <hip/hip_runtime.h>

// ---------------------------------------------------------------------------
// Pipeline (intermediates bf16, f32 accum; all big GEMMs on pipelined MFMA):
//   x (N,C,T,V) f32 --transpose--> XTP (N,T+2,V,C) bf16 (boundary frames = 0)
//   LNXP = LN(XTP, ln1)                  [26000 rows; 3x dedup vs (B,L)]
//   QKVP = LNXP @ [Wq|Wk|Wv] + b         [one MFMA dispatch, grid.y=3]
//   QA = QP @ Wqa + bqa                  [26000 x 8, dedup'd]
//   PQ = attpool<0>(QP rows, QA)         [fused softmax+pool, 1 block/b]
//   PK = attpool<1>(KP rows, PQ, Wka)    [fused logits+softmax+pool,
//                                         rotation-indexed LDS dot (no conflicts)]
//   ATT = [VPg*pk | QPg] @ [[Wt*Wp];[Wp]] + (bt*Wp+bp) + XTPg   [MFMA K=512]
//   F = LN(ATT); G = gelu(F@W1+b1); Y = G@W2+b2+ATT  [MFMA]
//   TN = LN(Y);  H = gelu(TN@c1w+c1b)                [MFMA]
//   out = H-window-contraction @ c2w + c2b           [MFMA K=768, float4
//                                                     transposed store]
// ---------------------------------------------------------------------------

#define DI __device__ __forceinline__

constexpr int CC   = 256;
constexpr int CL   = 75;
constexpr int CV   = 25;
constexpr int CT   = 128;
constexpr int TP   = 130;          // T+2 padded frames
constexpr int MPAD = 8 * TP * CV;  // 26000
constexpr int MBL  = 1024 * CL;    // 76800
constexpr int MOUT = 8 * CT * CV;  // 25600
constexpr float SM_SCALE = 0.17677669529663687f;  // 1/sqrt(32)

typedef __bf16 bf16x8 __attribute__((ext_vector_type(8)));
typedef float f32x4 __attribute__((ext_vector_type(4)));

DI float bf2f(unsigned short u) { return __uint_as_float(((unsigned)u) << 16); }
DI float bf2f_lo(unsigned u) { return __uint_as_float(u << 16); }
DI float bf2f_hi(unsigned u) { return __uint_as_float(u & 0xffff0000u); }
DI unsigned short f2bf(float f) {
  unsigned u = __float_as_uint(f);
  u += 0x7fffu + ((u >> 16) & 1u);
  return (unsigned short)(u >> 16);
}
DI unsigned packbf(float a, float b) {
  return (unsigned)f2bf(a) | ((unsigned)f2bf(b) << 16);
}
DI float geluf(float x) { return 0.5f * x * (1.f + erff(x * 0.70710678118654752440f)); }

// async global->LDS, 16B per lane (dest = wave-uniform base + lane*16)
DI void gll16(const unsigned short* g, unsigned short* l) {
  __builtin_amdgcn_global_load_lds(
      (const __attribute__((address_space(1))) unsigned int*)g,
      (__attribute__((address_space(3))) unsigned int*)l, 16, 0, 0);
}

// (B,L) row -> padded-frame row: r=(b,l), b=n*128+t, l=w*25+v -> (n*130+t+w)*25+v
DI int arow(int r) {
  int b = r / CL;
  int l = r - b * CL;
  int w = l / CV;
  int v = l - w * CV;
  int t = b & (CT - 1);
  int n = b >> 7;
  return (n * TP + t + w) * CV + v;
}

// ---- x (N,C,T,V) f32 -> XTP (N,T+2,V,C) bf16, interior frames ----
__global__ __launch_bounds__(256) void k_transpose(const float* __restrict__ x,
                                                   unsigned short* __restrict__ xtp) {
  __shared__ float tile[32][33];
  const int n = blockIdx.z;
  const int c0 = blockIdx.x * 32;
  const int tv0 = blockIdx.y * 32;
  const int tx = threadIdx.x & 31, ty = threadIdx.x >> 5;
#pragma unroll
  for (int j = 0; j < 32; j += 8) {
    tile[ty + j][tx] = x[((size_t)(n * CC + c0 + ty + j)) * 3200 + tv0 + tx];
  }
  __syncthreads();
#pragma unroll
  for (int j = 0; j < 32; j += 8) {
    int tv = tv0 + ty + j;
    int st = tv / CV, v = tv - st * CV;
    size_t row = ((size_t)n * TP + st + 1) * CV + v;
    xtp[row * CC + c0 + tx] = f2bf(tile[tx][ty + j]);
  }
}

// ---- zero the boundary frames (st = -1 and st = T) ----
__global__ __launch_bounds__(256) void k_zero_pad(unsigned short* __restrict__ xtp) {
  int i = blockIdx.x * 256 + threadIdx.x;  // 400*256 = 102400 exact
  int c = i & 255;
  int rid = i >> 8;
  int n = rid / 50;
  int rem = rid - n * 50;
  int side = rem / 25;
  int v = rem - side * 25;
  size_t row = ((size_t)n * TP + side * (TP - 1)) * CV + v;
  xtp[row * CC + c] = 0;
}

// ---- weight transpose+convert: dst[n*stride + off + k] = f2bf(src[k*256+n]) ----
struct TJobs {
  const float* src[10];
  unsigned short* dst[10];
  int stride[10];
  int off[10];
};
__global__ __launch_bounds__(256) void k_wtrans(TJobs J) {
  __shared__ float tile[32][33];
  const int j = blockIdx.z;
  const float* src = J.src[j];
  unsigned short* dst = J.dst[j];
  const int stride = J.stride[j], off = J.off[j];
  const int k0 = blockIdx.x * 32, n0 = blockIdx.y * 32;
  const int tx = threadIdx.x & 31, ty = threadIdx.x >> 5;
#pragma unroll
  for (int jj = 0; jj < 32; jj += 8)
    tile[ty + jj][tx] = src[(size_t)(k0 + ty + jj) * 256 + n0 + tx];
  __syncthreads();
#pragma unroll
  for (int jj = 0; jj < 32; jj += 8)
    dst[(size_t)(n0 + ty + jj) * stride + off + k0 + tx] = f2bf(tile[tx][ty + jj]);
}

// ---- WtWp[k][n] = sum_j Wt[k][j]*Wp[j][n] -> fused[n*512 + k] (bf16) ----
__global__ __launch_bounds__(256) void k_wtwp(const float* __restrict__ Wt,
                                              const float* __restrict__ Wp,
                                              unsigned short* __restrict__ fused) {
  __shared__ float wrow[256];
  const int k = blockIdx.x, n = threadIdx.x;
  wrow[n] = Wt[(size_t)k * 256 + n];
  __syncthreads();
  float acc = 0.f;
  for (int j = 0; j < 256; ++j) acc = fmaf(wrow[j], Wp[(size_t)j * 256 + n], acc);
  fused[(size_t)n * 512 + k] = f2bf(acc);
}

// ---- bias2[n] = bp[n] + sum_k bt[k]*Wp[k][n]; also bias3 = [bq|bk|bv] ----
__global__ __launch_bounds__(256) void k_bias2(const float* __restrict__ bt,
                                               const float* __restrict__ Wp,
                                               const float* __restrict__ bp,
                                               const float* __restrict__ bq,
                                               const float* __restrict__ bk,
                                               const float* __restrict__ bv,
                                               float* __restrict__ bias2,
                                               float* __restrict__ bias3) {
  const int n = threadIdx.x;
  float acc = bp[n];
  for (int j = 0; j < 256; ++j) acc = fmaf(bt[j], Wp[(size_t)j * 256 + n], acc);
  bias2[n] = acc;
  bias3[n] = bq[n];
  bias3[256 + n] = bk[n];
  bias3[512 + n] = bv[n];
}

// ---- LayerNorm: one wave per row, 4 rows per block ----
__global__ __launch_bounds__(256) void k_ln4(const unsigned short* __restrict__ X,
                                             const float* __restrict__ g,
                                             const float* __restrict__ b,
                                             unsigned short* __restrict__ Y) {
  const int row = blockIdx.x * 4 + (threadIdx.x >> 6);
  const int lane = threadIdx.x & 63;
  const uint2 u = *(const uint2*)(X + (size_t)row * CC + lane * 4);
  const float x0 = bf2f_lo(u.x), x1 = bf2f_hi(u.x), x2 = bf2f_lo(u.y), x3 = bf2f_hi(u.y);
  float s = x0 + x1 + x2 + x3;
  float q = x0 * x0 + x1 * x1 + x2 * x2 + x3 * x3;
#pragma unroll
  for (int o = 32; o; o >>= 1) { s += __shfl_xor(s, o); q += __shfl_xor(q, o); }
  const float mean = s * (1.f / CC);
  const float var = q * (1.f / CC) - mean * mean;
  const float rs = rsqrtf(var + 1e-5f);
  const float4 g4 = *(const float4*)(g + lane * 4);
  const float4 b4 = *(const float4*)(b + lane * 4);
  uint2 o2;
  o2.x = packbf((x0 - mean) * rs * g4.x + b4.x, (x1 - mean) * rs * g4.y + b4.y);
  o2.y = packbf((x2 - mean) * rs * g4.z + b4.z, (x3 - mean) * rs * g4.w + b4.w);
  *(uint2*)(Y + (size_t)row * CC + lane * 4) = o2;
}

// ---- pipelined MFMA bf16 GEMM: BM=64, BN=256, BK=32, 512 thr, dbuf LDS ----
// AMODE 0: direct (A via global_load_lds);
//       5: fused ATT A = [VPg*pk | QPg] (KD=512); 4: H window gather (KD=768)
// EPI: 0 bias; 1 gelu(acc+bias); 2 +addSrc[r]; 3 +addSrc[arow(r)];
//      4 float4 transposed f32 store out[n,col,rr]
// MULTI: blockIdx.y selects weight/bias/output slab (QKV fusion)
template <int AMODE, int EPI, int KD, bool MULTI>
__global__ __launch_bounds__(512) void k_mgemm(const unsigned short* __restrict__ A,
                                               const unsigned short* __restrict__ A2,
                                               const float* __restrict__ scaleVec,
                                               const unsigned short* __restrict__ BwT,
                                               const float* __restrict__ bias,
                                               const unsigned short* __restrict__ addSrc,
                                               unsigned short* __restrict__ Cout,
                                               float* __restrict__ FOut,
                                               int M) {
  if constexpr (MULTI) {
    const int z = blockIdx.y;
    BwT += (size_t)z * (256 * 256);
    bias += z * 256;
    Cout += (size_t)z * MPAD * CC;
  }
  __shared__ unsigned short As[2][64 * 32];
  __shared__ unsigned short Bs[2][256 * 32];
  const int tid = threadIdx.x;
  const int lane = tid & 63;
  const int wid = tid >> 6;
  const int wm = wid >> 2, wn = wid & 3;  // 2x4 waves, wave tile 32x64
  const int r0 = blockIdx.x * 64;
  f32x4 acc[2][4] = {};

  // A staging state: threads 0..255, one 16B chunk each
  const bool sa = tid < 256;
  const int rA = r0 + (tid >> 2);
  const int seg8 = (tid & 3) * 8;
  const bool valid = sa && (rA < M);
  int ar = 0, bb = 0, hrb = 0;
  if (valid) {
    if (AMODE == 5) { ar = arow(rA); bb = rA / CL; }
    if (AMODE == 4) {
      const int nb = rA / 3200, rr = rA - nb * 3200;
      const int tq = rr / 25, vq = rr - tq * 25;
      hrb = (nb * CT + tq) * CL + vq;
    }
  }

  auto scale_pack = [&](uint4 t4, const float* sv) -> uint4 {
    const float4 s0 = *(const float4*)sv;
    const float4 s1 = *(const float4*)(sv + 4);
    uint4 o;
    o.x = packbf(bf2f_lo(t4.x) * s0.x, bf2f_hi(t4.x) * s0.y);
    o.y = packbf(bf2f_lo(t4.y) * s0.z, bf2f_hi(t4.y) * s0.w);
    o.z = packbf(bf2f_lo(t4.z) * s1.x, bf2f_hi(t4.z) * s1.y);
    o.w = packbf(bf2f_lo(t4.w) * s1.z, bf2f_hi(t4.w) * s1.w);
    return o;
  };
  auto loadA = [&](int k0) -> uint4 {
    uint4 u = make_uint4(0, 0, 0, 0);
    if (!valid) return u;
    if (AMODE == 5) {
      if (k0 < 256) {
        const int kg = k0 + seg8;
        u = scale_pack(*(const uint4*)(A + (size_t)ar * CC + kg), scaleVec + bb * CC + kg);
      } else {
        u = *(const uint4*)(A2 + (size_t)ar * CC + (k0 - 256) + seg8);
      }
    } else if (AMODE == 4) {
      const int w = k0 >> 8;
      u = *(const uint4*)(A + (size_t)(hrb + w * CV) * CC + (k0 & 255) + seg8);
    }
    return u;
  };
  auto stageB = [&](int buf, int k0) {
#pragma unroll
    for (int pp = 0; pp < 2; ++pp) {
      const int s = tid + pp * 512;
      gll16(BwT + (size_t)(s >> 2) * KD + k0 + (s & 3) * 8, &Bs[buf][s * 8]);
    }
  };
  auto stageAg = [&](int buf, int k0) {
    if (valid) gll16(A + (size_t)rA * CC + k0 + seg8, &As[buf][tid * 8]);
  };

  // prologue: stage K-step 0 into buffer 0
  stageB(0, 0);
  if constexpr (AMODE == 0) {
    stageAg(0, 0);
  } else {
    const uint4 a0 = loadA(0);
    if (sa) *(uint4*)(&As[0][tid * 8]) = a0;
  }
  __syncthreads();

  constexpr int NT = KD / 32;
  int cur = 0;
  for (int t = 0; t < NT; ++t) {
    const int nxt = cur ^ 1;
    const bool more = (t + 1 < NT);
    uint4 an;
    if (more) {  // issue next-tile stage BEFORE compute (latency hides under MFMA)
      stageB(nxt, (t + 1) * 32);
      if constexpr (AMODE == 0) stageAg(nxt, (t + 1) * 32);
      else an = loadA((t + 1) * 32);
    }
    bf16x8 af[2], bfr[4];
#pragma unroll
    for (int mi = 0; mi < 2; ++mi)
      af[mi] = *(const bf16x8*)(&As[cur][(wm * 32 + mi * 16 + (lane & 15)) * 32 + (lane >> 4) * 8]);
#pragma unroll
    for (int ni = 0; ni < 4; ++ni)
      bfr[ni] = *(const bf16x8*)(&Bs[cur][(wn * 64 + ni * 16 + (lane & 15)) * 32 + (lane >> 4) * 8]);
#pragma unroll
    for (int mi = 0; mi < 2; ++mi)
#pragma unroll
      for (int ni = 0; ni < 4; ++ni)
        acc[mi][ni] = __builtin_amdgcn_mfma_f32_16x16x32_bf16(af[mi], bfr[ni], acc[mi][ni], 0, 0, 0);
    if (more) {
      if constexpr (AMODE != 0) {
        if (sa) *(uint4*)(&As[nxt][tid * 8]) = an;  // vmcnt wait auto-inserted
      }
      __syncthreads();  // drains vmcnt (B gll) + lgkm (A ds_write)
      cur = nxt;
    }
  }

  const int ln15 = lane & 15, lq = lane >> 4;
#pragma unroll
  for (int mi = 0; mi < 2; ++mi) {
#pragma unroll
    for (int ni = 0; ni < 4; ++ni) {
      const int col = wn * 64 + ni * 16 + ln15;
      const float bcol = bias[col];
      if constexpr (EPI == 4) {
        const int rbase = r0 + wm * 32 + mi * 16 + lq * 4;
        const int nb = rbase / 3200, rr = rbase - nb * 3200;
        float4 v;
        v.x = acc[mi][ni][0] + bcol;
        v.y = acc[mi][ni][1] + bcol;
        v.z = acc[mi][ni][2] + bcol;
        v.w = acc[mi][ni][3] + bcol;
        *(float4*)(FOut + (size_t)nb * 819200 + (size_t)col * 3200 + rr) = v;
      } else {
#pragma unroll
        for (int rg = 0; rg < 4; ++rg) {
          const int r = r0 + wm * 32 + mi * 16 + lq * 4 + rg;
          if (r >= M) continue;
          float v = acc[mi][ni][rg] + bcol;
          if (EPI == 1) v = geluf(v);
          else if (EPI == 2) v += bf2f(addSrc[(size_t)r * CC + col]);
          else if (EPI == 3) v += bf2f(addSrc[(size_t)arow(r) * CC + col]);
          Cout[(size_t)r * CC + col] = f2bf(v);
        }
      }
    }
  }
}

// ---- rows x (256 -> 8) projection (QA), one wave per row, 4 rows/block ----
__global__ __launch_bounds__(256) void k_proj8(const unsigned short* __restrict__ SRC,
                                               const float* __restrict__ Wsm,
                                               const float* __restrict__ bsm,
                                               float* __restrict__ OUT) {
  const int r = blockIdx.x * 4 + (threadIdx.x >> 6);
  const int lane = threadIdx.x & 63;
  const int c = lane * 4;
  const uint2 u = *(const uint2*)(SRC + (size_t)r * CC + c);
  const float m0 = bf2f_lo(u.x), m1 = bf2f_hi(u.x), m2 = bf2f_lo(u.y), m3 = bf2f_hi(u.y);
  float p[8] = {};
#pragma unroll
  for (int j = 0; j < 4; ++j) {
    const float mj = (j == 0) ? m0 : (j == 1) ? m1 : (j == 2) ? m2 : m3;
#pragma unroll
    for (int h = 0; h < 8; ++h) p[h] += mj * Wsm[(c + j) * 8 + h];
  }
#pragma unroll
  for (int h = 0; h < 8; ++h) {
#pragma unroll
    for (int o = 32; o; o >>= 1) p[h] += __shfl_down(p[h], o);
  }
  if (lane == 0) {
#pragma unroll
    for (int h = 0; h < 8; ++h) OUT[(size_t)r * 8 + h] = p[h] + bsm[h];
  }
}

// ---- fused attention pool: one block per b (1024 blocks, 256 threads) ----
// SIDE 0 (Q): logits gathered from QA[26000][8]; OUT[b][c] = sum_l sm(qa)[h(c)][l]*ROWS[ar(l)][c]
// SIDE 1 (K): logits = (ROWS[ar(l)] .* PQ[b]) @ Wka + bka, scaled; pool same with KP.
// K-side dot uses per-lane channel rotation: lanes read consecutive c/2 words
// -> 32 banks covered, 2 lanes/bank (conflict-free; was 32-way at fixed c).
template <int SIDE>
__global__ __launch_bounds__(256) void k_attpool(const unsigned short* __restrict__ ROWS,
                                                 const float* __restrict__ QA,
                                                 const float* __restrict__ PQ,
                                                 const float* __restrict__ Wka,
                                                 const float* __restrict__ bka,
                                                 float* __restrict__ OUT) {
  __shared__ unsigned short rows[CL * CC];                   // 38400 B
  __shared__ float uu[(SIDE == 1) ? 8 * 258 : 8];            // [h][c] strided 258
  __shared__ float lg[8 * 76];                               // logits per (h,l)
  __shared__ float inv8[8];
  __shared__ int arl[CL];
  const int b = blockIdx.x;
  const int t = threadIdx.x;

  if (t < CL) arl[t] = arow(b * CL + t);
  __syncthreads();

  // stage the 75 gathered rows via global_load_lds (dest lane-linear: rows+i*16B)
  for (int i = t; i < CL * 32; i += 256) {
    const int r = i >> 5, seg = i & 31;
    gll16(ROWS + (size_t)arl[r] * CC + seg * 8, &rows[i * 8]);
  }
  if constexpr (SIDE == 0) {
    // logits straight from QA gather: 75 rows x 8 f32 (two float4 per row)
    for (int i = t; i < CL * 2; i += 256) {
      const int l = i >> 1, q = i & 1;
      const float4 v = *(const float4*)(QA + (size_t)arl[l] * 8 + q * 4);
      lg[(q * 4 + 0) * 76 + l] = v.x * SM_SCALE;
      lg[(q * 4 + 1) * 76 + l] = v.y * SM_SCALE;
      lg[(q * 4 + 2) * 76 + l] = v.z * SM_SCALE;
      lg[(q * 4 + 3) * 76 + l] = v.w * SM_SCALE;
    }
  } else {
    for (int i = t; i < CC * 8; i += 256) {
      const int c = i >> 3, h = i & 7;
      uu[h * 258 + c] = PQ[(size_t)b * CC + c] * Wka[c * 8 + h];
    }
  }
  __syncthreads();

  if constexpr (SIDE == 1) {
    // 600 dot-256 products from LDS, rotation-indexed (conflict-free rows reads)
    const int c0 = (t & 127) * 2;
    for (int i = t; i < CL * 8; i += 256) {
      const int h = i / CL, l = i - h * CL;
      float acc = bka[h];
#pragma unroll 4
      for (int jj = 0; jj < CC; jj += 2) {
        const int c = (c0 + jj) & 255;
        const unsigned pr = *(const unsigned*)&rows[l * CC + c];
        acc = fmaf(bf2f_lo(pr), uu[h * 258 + c], acc);
        acc = fmaf(bf2f_hi(pr), uu[h * 258 + c + 1], acc);
      }
      lg[h * 76 + l] = acc * SM_SCALE;
    }
    __syncthreads();
  }

  // softmax over l per h (8 threads, 75 serial — negligible vs dot phase)
  if (t < 8) {
    float m = -1e30f;
    for (int l = 0; l < CL; ++l) m = fmaxf(m, lg[t * 76 + l]);
    float s = 0.f;
    for (int l = 0; l < CL; ++l) {
      const float e = __expf(lg[t * 76 + l] - m);
      lg[t * 76 + l] = e;
      s += e;
    }
    inv8[t] = 1.f / s;
  }
  __syncthreads();

  // pool: thread c: OUT[b][c] = inv * sum_l e[h(c)][l] * rows[l][c]
  {
    const int h = t >> 5;
    float acc = 0.f;
    for (int l = 0; l < CL; ++l) acc = fmaf(lg[h * 76 + l], bf2f(rows[l * CC + t]), acc);
    OUT[(size_t)b * CC + t] = acc * inv8[h];
  }
}

extern "C" void kernel_launch(void* const* d_in, const int* in_sizes, int n_in,
                              void* d_out, int out_size, void* d_ws, size_t ws_size,
                              hipStream_t stream) {
  const float* x = (const float*)d_in[0];
  const float* ln1_g = (const float*)d_in[1];
  const float* ln1_b = (const float*)d_in[2];
  const float* Wq = (const float*)d_in[3];
  const float* bq = (const float*)d_in[4];
  const float* Wqa = (const float*)d_in[5];
  const float* bqa = (const float*)d_in[6];
  const float* Wk = (const float*)d_in[7];
  const float* bk = (const float*)d_in[8];
  const float* Wka = (const float*)d_in[9];
  const float* bka = (const float*)d_in[10];
  const float* Wv = (const float*)d_in[11];
  const float* bv = (const float*)d_in[12];
  const float* Wt = (const float*)d_in[13];
  const float* bt = (const float*)d_in[14];
  const float* Wp = (const float*)d_in[15];
  const float* bp = (const float*)d_in[16];
  const float* ffn_g = (const float*)d_in[17];
  const float* ffn_b = (const float*)d_in[18];
  const float* W1 = (const float*)d_in[19];
  const float* b1 = (const float*)d_in[20];
  const float* W2 = (const float*)d_in[21];
  const float* b2 = (const float*)d_in[22];
  const float* tn_g = (const float*)d_in[23];
  const float* tn_b = (const float*)d_in[24];
  const float* c1w = (const float*)d_in[25];
  const float* c1b = (const float*)d_in[26];
  const float* c2w = (const float*)d_in[27];
  const float* c2b = (const float*)d_in[28];
  float* out = (float*)d_out;

  char* wp = (char*)d_ws;
  auto alloc = [&](size_t bytes) -> char* {
    char* p = wp;
    wp += (bytes + 255) & ~(size_t)255;
    return p;
  };
  unsigned short* XTP = (unsigned short*)alloc((size_t)MPAD * CC * 2);
  unsigned short* LNXP = (unsigned short*)alloc((size_t)MPAD * CC * 2);
  unsigned short* QKVP = (unsigned short*)alloc((size_t)3 * MPAD * CC * 2);
  unsigned short* QP = QKVP;
  unsigned short* KP = QKVP + (size_t)MPAD * CC;
  unsigned short* VP = QKVP + (size_t)2 * MPAD * CC;
  unsigned short* KVb = (unsigned short*)alloc((size_t)MBL * CC * 2);   // F / TN
  unsigned short* ATTb = (unsigned short*)alloc((size_t)MBL * CC * 2);  // ATT -> H
  unsigned short* Gb = (unsigned short*)alloc((size_t)MBL * CC * 2);
  unsigned short* Yb = (unsigned short*)alloc((size_t)MBL * CC * 2);
  float* QA = (float*)alloc((size_t)MPAD * 8 * 4);
  float* PQ = (float*)alloc((size_t)1024 * CC * 4);
  float* PK = (float*)alloc((size_t)1024 * CC * 4);
  unsigned short* WqkvT = (unsigned short*)alloc((size_t)3 * 256 * 256 * 2);
  unsigned short* W1T = (unsigned short*)alloc(256 * 256 * 2);
  unsigned short* W2T = (unsigned short*)alloc(256 * 256 * 2);
  unsigned short* c1wT = (unsigned short*)alloc(256 * 256 * 2);
  unsigned short* c2wT = (unsigned short*)alloc(256 * 768 * 2);
  unsigned short* fusedB = (unsigned short*)alloc(256 * 512 * 2);  // [WtWp | Wp]^T
  float* bias2 = (float*)alloc(256 * 4);
  float* bias3 = (float*)alloc(768 * 4);

  // weight prep: dst[n*stride+off+k] = bf16(src[k][n])
  TJobs J;
  const float* srcs[10] = {Wq, Wk, Wv, W1, W2, c1w, c2w, c2w + 65536, c2w + 131072, Wp};
  unsigned short* dsts[10] = {WqkvT, WqkvT + 65536, WqkvT + 131072, W1T, W2T, c1wT,
                              c2wT, c2wT, c2wT, fusedB};
  const int strides[10] = {256, 256, 256, 256, 256, 256, 768, 768, 768, 512};
  const int offs[10] = {0, 0, 0, 0, 0, 0, 0, 256, 512, 256};
  for (int i = 0; i < 10; ++i) {
    J.src[i] = srcs[i]; J.dst[i] = dsts[i]; J.stride[i] = strides[i]; J.off[i] = offs[i];
  }
  k_wtrans<<<dim3(8, 8, 10), 256, 0, stream>>>(J);
  k_wtwp<<<256, 256, 0, stream>>>(Wt, Wp, fusedB);
  k_bias2<<<1, 256, 0, stream>>>(bt, Wp, bp, bq, bk, bv, bias2, bias3);

  k_transpose<<<dim3(8, 100, 8), 256, 0, stream>>>(x, XTP);
  k_zero_pad<<<400, 256, 0, stream>>>(XTP);
  k_ln4<<<MPAD / 4, 256, 0, stream>>>(XTP, ln1_g, ln1_b, LNXP);

  const int gP = (MPAD + 63) / 64;  // 407
  const int gB = MBL / 64;          // 1200
  const int gO = MOUT / 64;         // 400
  // fused QKV: grid.y = 3 slabs
  k_mgemm<0, 0, 256, true><<<dim3(gP, 3), 512, 0, stream>>>(
      LNXP, nullptr, nullptr, WqkvT, bias3, nullptr, QKVP, nullptr, MPAD);

  k_proj8<<<MPAD / 4, 256, 0, stream>>>(QP, Wqa, bqa, QA);
  k_attpool<0><<<1024, 256, 0, stream>>>(QP, QA, nullptr, nullptr, nullptr, PQ);
  k_attpool<1><<<1024, 256, 0, stream>>>(KP, nullptr, PQ, Wka, bka, PK);

  // ATT = [VPg*pk | QPg] @ [[WtWp];[Wp]] + bias2 + XTPg
  k_mgemm<5, 3, 512, false><<<gB, 512, 0, stream>>>(VP, QP, PK, fusedB, bias2, XTP, ATTb, nullptr, MBL);

  k_ln4<<<MBL / 4, 256, 0, stream>>>(ATTb, ffn_g, ffn_b, KVb);  // F
  k_mgemm<0, 1, 256, false><<<gB, 512, 0, stream>>>(KVb, nullptr, nullptr, W1T, b1, nullptr, Gb, nullptr, MBL);
  k_mgemm<0, 2, 256, false><<<gB, 512, 0, stream>>>(Gb, nullptr, nullptr, W2T, b2, ATTb, Yb, nullptr, MBL);

  k_ln4<<<MBL / 4, 256, 0, stream>>>(Yb, tn_g, tn_b, KVb);  // TN
  k_mgemm<0, 1, 256, false><<<gB, 512, 0, stream>>>(KVb, nullptr, nullptr, c1wT, c1b, nullptr, ATTb, nullptr, MBL);  // H

  k_mgemm<4, 4, 768, false><<<gO, 512, 0, stream>>>(ATTb, nullptr, nullptr, c2wT, c2b, nullptr, nullptr, out, MOUT);
}